// Round 7
// baseline (3103.206 us; speedup 1.0000x reference)
//
#include <hip/hip_runtime.h>
#include <hip/hip_bf16.h>
#include <math.h>

#define NN 4096
#define EE 65536
#define HH 128
#define EDD 64
#define THD 512

typedef __bf16 bf16;

// ---------------------------------------------------------------------------
// float-input dtype detect (R4; proven to select f32 on this harness)
// ---------------------------------------------------------------------------
__global__ __launch_bounds__(64) void k_detect(const void* __restrict__ p,
                                               int* __restrict__ flag)
{
    const bf16* b = (const bf16*)p;
    int t = threadIdx.x;
    int bad = 0;
    for (int i = 0; i < 32; i++) {
        float v = (float)b[t * 32 + i];
        if (!(v == v) || fabsf(v) > 100.f) bad = 1;
    }
    unsigned long long m = __ballot(bad);
    if (t == 0) *flag = (m == 0ULL) ? 1 : 0;
}

__global__ void k_canon_f(const void* __restrict__ src, float* __restrict__ dst,
                          int n, const int* __restrict__ flag)
{
    int i = blockIdx.x * 256 + threadIdx.x;
    if (i >= n) return;
    dst[i] = (*flag) ? (float)((const bf16*)src)[i] : ((const float*)src)[i];
}

// ---------------------------------------------------------------------------
// edge_index layout detect (R6; proven to select int32 on this harness)
// ---------------------------------------------------------------------------
__global__ __launch_bounds__(64) void k_detidx(const int* __restrict__ p,
                                               int* __restrict__ iflag)
{
    int t = threadIdx.x;
    int bad = 0;
    for (int i = 0; i < 8; i++) {
        int k = t * 8 + i;
        int lo = p[2 * k], hi = p[2 * k + 1];
        if (hi != 0 || lo < 0 || lo >= NN) bad = 1;
    }
    unsigned long long m = __ballot(bad);
    if (t == 0) *iflag = (m == 0ULL) ? 1 : 0;
}

__global__ void k_extidx(const int* __restrict__ p, int* __restrict__ srcW,
                         int* __restrict__ dstW, const int* __restrict__ iflag)
{
    int e = blockIdx.x * 256 + threadIdx.x;
    int s, d;
    if (*iflag) { s = p[2 * e];  d = p[2 * EE + 2 * e]; }
    else        { s = p[e];      d = p[EE + e]; }
    srcW[e] = min(max(s, 0), NN - 1);
    dstW[e] = min(max(d, 0), NN - 1);
}

// ---------------------------------------------------------------------------
// VALU GEMM: C[M,Nout] = act(A[M,K] @ W[Nout,K]^T + bias)
// AMODE 0: A f32 ; 1: A bf16 ;
//       2: A row e = relu(SA[src[e]] + SB[dst[e]] + b1)                (K=256)
//       3: A row e = [ Xn[dst[e]] | Xn[src[e]] | Eenc[e] ]             (K=384)
// ---------------------------------------------------------------------------
template<int AMODE, bool RELU, bool OUTBF>
__global__ __launch_bounds__(256) void k_vgemm(
    const void* __restrict__ Av, int lda,
    const float* __restrict__ SA, const float* __restrict__ SB,
    const float* __restrict__ b1,
    const float* __restrict__ Xn, const bf16* __restrict__ Eenc,
    const int* __restrict__ src, const int* __restrict__ dst,
    const float* __restrict__ W, int ldw, const float* __restrict__ bias,
    void* __restrict__ Cv, int ldc, int K)
{
    __shared__ float As[64][33];
    __shared__ float Ws[64][33];
    const int m0 = blockIdx.x * 64, n0 = blockIdx.y * 64;
    const int tid = threadIdx.x;
    const int ty = tid >> 4, tx = tid & 15;
    const int lrow = tid >> 2, lcol = (tid & 3) * 8;
    float acc[4][4] = {{0,0,0,0},{0,0,0,0},{0,0,0,0},{0,0,0,0}};

    int sI = 0, dI = 0;
    if (AMODE == 2 || AMODE == 3) { sI = src[m0 + lrow]; dI = dst[m0 + lrow]; }

    for (int k0 = 0; k0 < K; k0 += 32) {
        if (AMODE == 0) {
            const float* Ap = (const float*)Av + (size_t)(m0 + lrow) * lda + k0 + lcol;
#pragma unroll
            for (int j = 0; j < 8; j++) As[lrow][lcol + j] = Ap[j];
        } else if (AMODE == 1) {
            const bf16* Ap = (const bf16*)Av + (size_t)(m0 + lrow) * lda + k0 + lcol;
#pragma unroll
            for (int j = 0; j < 8; j++) As[lrow][lcol + j] = (float)Ap[j];
        } else if (AMODE == 2) {
#pragma unroll
            for (int j = 0; j < 8; j++) {
                int c = k0 + lcol + j;
                float v = SA[(size_t)sI * 256 + c] + SB[(size_t)dI * 256 + c] + b1[c];
                As[lrow][lcol + j] = fmaxf(v, 0.f);
            }
        } else {  // AMODE 3: h = [x_dst | x_src | enc_e]
            int c0 = k0 + lcol;
            if (c0 < 128) {
                const float* p = Xn + (size_t)dI * 128 + c0;
#pragma unroll
                for (int j = 0; j < 8; j++) As[lrow][lcol + j] = p[j];
            } else if (c0 < 256) {
                const float* p = Xn + (size_t)sI * 128 + (c0 - 128);
#pragma unroll
                for (int j = 0; j < 8; j++) As[lrow][lcol + j] = p[j];
            } else {
                const bf16* p = Eenc + (size_t)(m0 + lrow) * 128 + (c0 - 256);
#pragma unroll
                for (int j = 0; j < 8; j++) As[lrow][lcol + j] = (float)p[j];
            }
        }
        {
            const float* Wp = W + (size_t)(n0 + lrow) * ldw + k0 + lcol;
#pragma unroll
            for (int j = 0; j < 8; j++) Ws[lrow][lcol + j] = Wp[j];
        }
        __syncthreads();
#pragma unroll 4
        for (int kk = 0; kk < 32; kk++) {
            float a0 = As[ty * 4 + 0][kk], a1 = As[ty * 4 + 1][kk];
            float a2 = As[ty * 4 + 2][kk], a3 = As[ty * 4 + 3][kk];
            float w0 = Ws[tx * 4 + 0][kk], w1 = Ws[tx * 4 + 1][kk];
            float w2 = Ws[tx * 4 + 2][kk], w3 = Ws[tx * 4 + 3][kk];
            acc[0][0] += a0 * w0; acc[0][1] += a0 * w1; acc[0][2] += a0 * w2; acc[0][3] += a0 * w3;
            acc[1][0] += a1 * w0; acc[1][1] += a1 * w1; acc[1][2] += a1 * w2; acc[1][3] += a1 * w3;
            acc[2][0] += a2 * w0; acc[2][1] += a2 * w1; acc[2][2] += a2 * w2; acc[2][3] += a2 * w3;
            acc[3][0] += a3 * w0; acc[3][1] += a3 * w1; acc[3][2] += a3 * w2; acc[3][3] += a3 * w3;
        }
        __syncthreads();
    }
#pragma unroll
    for (int r = 0; r < 4; r++) {
        int gm = m0 + ty * 4 + r;
#pragma unroll
        for (int c = 0; c < 4; c++) {
            int gn = n0 + tx * 4 + c;
            float v = acc[r][c] + (bias ? bias[gn] : 0.f);
            if (RELU) v = fmaxf(v, 0.f);
            if (OUTBF) ((bf16*)Cv)[(size_t)gm * ldc + gn] = (bf16)v;
            else       ((float*)Cv)[(size_t)gm * ldc + gn] = v;
        }
    }
}

// ----------------------- CSR build -----------------------------------------
__global__ void k_count(const int* __restrict__ dst, int* __restrict__ counts)
{
    int e = blockIdx.x * 256 + threadIdx.x;
    atomicAdd(&counts[dst[e]], 1);
}

__global__ __launch_bounds__(1024) void k_scan(
    const int* __restrict__ counts, int* __restrict__ offs, int* __restrict__ cursor)
{
    __shared__ int ls[1024];
    int tid = threadIdx.x, base = tid * 4;
    int c0 = counts[base], c1 = counts[base + 1], c2 = counts[base + 2], c3 = counts[base + 3];
    ls[tid] = c0 + c1 + c2 + c3;
    __syncthreads();
    for (int d = 1; d < 1024; d <<= 1) {
        int v = (tid >= d) ? ls[tid - d] : 0;
        __syncthreads();
        ls[tid] += v;
        __syncthreads();
    }
    int r = tid ? ls[tid - 1] : 0;
    offs[base] = r;     cursor[base] = r;     r += c0;
    offs[base + 1] = r; cursor[base + 1] = r; r += c1;
    offs[base + 2] = r; cursor[base + 2] = r; r += c2;
    offs[base + 3] = r; cursor[base + 3] = r; r += c3;
    if (tid == 1023) offs[4096] = r;
}

__global__ void k_fill(const int* __restrict__ dst, int* __restrict__ cursor,
                       int* __restrict__ eord)
{
    int e = blockIdx.x * 256 + threadIdx.x;
    int p = atomicAdd(&cursor[dst[e]], 1);
    eord[p] = e;
}

// ---------------------------------------------------------------------------
// Direct aggregation over msg rows (tower-slice ts). grid=N, block=128.
// ---------------------------------------------------------------------------
__global__ __launch_bounds__(128) void k_aggd(
    const float* __restrict__ msg,
    const int* __restrict__ offs, const int* __restrict__ eord,
    float* __restrict__ aggX, float* __restrict__ aggS, float* __restrict__ aggM,
    int ts)
{
    int n = blockIdx.x, tid = threadIdx.x;
    float s = 0.f, q = 0.f, x = -3e38f;
    int beg = offs[n], end = offs[n + 1];
    for (int i = beg; i < end; i++) {
        float m = msg[(size_t)eord[i] * 128 + tid];
        s += m; q += m * m; x = fmaxf(x, m);
    }
    int cnt = end - beg;
    float inv = 1.f / fmaxf((float)cnt, 1.f);
    float me = s * inv;
    float v = fmaxf(q * inv - me * me, 0.f);
    size_t o = (size_t)n * THD + ts * 128 + tid;
    aggX[o] = cnt > 0 ? x : 0.f;
    aggS[o] = sqrtf(v + 1e-5f);
    aggM[o] = me;
}

// ---------------------------------------------------------------------------
// Post-MLP + lin + relu. grid=N, block=128 (tid = t*32+fo).
// ---------------------------------------------------------------------------
__global__ __launch_bounds__(128) void k_post(
    const float* __restrict__ xin,
    const float* __restrict__ aggX, const float* __restrict__ aggS,
    const float* __restrict__ aggM,
    const float* __restrict__ qW, const float* __restrict__ qb,
    const float* __restrict__ lW, const float* __restrict__ lb,
    float* __restrict__ mout)
{
    __shared__ float cat[2048];
    __shared__ float ysh[128];
    int n = blockIdx.x, tid = threadIdx.x;
    float xv = xin[(size_t)n * HH + tid];
#pragma unroll
    for (int t = 0; t < 4; t++) {
        cat[t * 512 + tid]       = xv;
        cat[t * 512 + 128 + tid] = aggX[(size_t)n * THD + t * 128 + tid];
        cat[t * 512 + 256 + tid] = aggS[(size_t)n * THD + t * 128 + tid];
        cat[t * 512 + 384 + tid] = aggM[(size_t)n * THD + t * 128 + tid];
    }
    __syncthreads();
    const float4* wr = (const float4*)(qW + (size_t)tid * 512);
    const float* crow = &cat[(tid >> 5) * 512];
    float acc = qb[tid];
    for (int c4i = 0; c4i < 128; c4i++) {
        float4 w4 = wr[c4i];
        acc += crow[c4i * 4 + 0] * w4.x + crow[c4i * 4 + 1] * w4.y
             + crow[c4i * 4 + 2] * w4.z + crow[c4i * 4 + 3] * w4.w;
    }
    ysh[tid] = acc;
    __syncthreads();
    const float4* lr = (const float4*)(lW + (size_t)tid * 128);
    float a2 = lb[tid];
    for (int c4i = 0; c4i < 32; c4i++) {
        float4 w4 = lr[c4i];
        a2 += ysh[c4i * 4 + 0] * w4.x + ysh[c4i * 4 + 1] * w4.y
            + ysh[c4i * 4 + 2] * w4.z + ysh[c4i * 4 + 3] * w4.w;
    }
    mout[(size_t)n * HH + tid] = fmaxf(a2, 0.f);
}

// --------------------------- GRU elementwise --------------------------------
__global__ void k_gru(const float* __restrict__ gi, const float* __restrict__ gh,
                      float* __restrict__ hst)
{
    int i = blockIdx.x * 256 + threadIdx.x;
    int k = i & 127;
    size_t b = (size_t)(i >> 7) * 384;
    float ir = gi[b + k],       hr = gh[b + k];
    float iz = gi[b + 128 + k], hz = gh[b + 128 + k];
    float ic = gi[b + 256 + k], hc = gh[b + 256 + k];
    float r = 1.f / (1.f + __expf(-(ir + hr)));
    float z = 1.f / (1.f + __expf(-(iz + hz)));
    float c = tanhf(ic + r * hc);
    float h = hst[i];
    hst[i] = (1.f - z) * c + z * h;
}

__global__ void k_copy_ea(const float* __restrict__ ea, bf16* __restrict__ cat)
{
    int i = blockIdx.x * 256 + threadIdx.x;
    int e = i >> 6, d = i & 63;
    cat[(size_t)e * 192 + 128 + d] = (bf16)ea[i];
}

// ---- f32 OUTPUT (reference's output dtype is float32) ----
__global__ void k_writeout(const float* __restrict__ of, const float* __restrict__ ea,
                           float* __restrict__ o)
{
    size_t i = (size_t)blockIdx.x * 256 + threadIdx.x;   // 5242880 total
    if (i < 524288)            o[i] = of[i];
    else if (i < 4718592)      o[i] = ea[i - 524288];
    else                       o[i] = of[i - 4718592];
}

// diagnostic sentinel (f32 now): Output 0 <- value
__global__ void k_sentinel(float* __restrict__ o, float v)
{
    int i = blockIdx.x * 256 + threadIdx.x;
    o[i] = v;
}

// ===========================================================================
extern "C" void kernel_launch(void* const* d_in, const int* in_sizes, int n_in,
                              void* d_out, int out_size, void* d_ws, size_t ws_size,
                              hipStream_t stream)
{
    static const int exp_sizes[23] = {
        524288, 4194304, 131072, 24576, 384, 589824, 1536, 196608, 384,
        49152, 384, 49152, 49152, 384, 384, 65536, 256, 32768, 128,
        24576, 128, 8192, 64 };
    if (n_in != 23) {
        k_sentinel<<<2048, 256, 0, stream>>>((float*)d_out, 200.f);
        return;
    }
    for (int i = 0; i < 23; i++) {
        if (in_sizes[i] != exp_sizes[i]) {
            k_sentinel<<<2048, 256, 0, stream>>>((float*)d_out, 60.f + 4.f * i);
            return;
        }
    }
    if (out_size != 5242880) {
        k_sentinel<<<2048, 256, 0, stream>>>((float*)d_out, 52.f);
        return;
    }

    const int* eidx = (const int*)d_in[2];

    char* w = (char*)d_ws;
    size_t off = 0;
    auto alloc = [&](size_t bytes) -> char* {
        char* p = w + off;
        off = (off + bytes + 255) & ~(size_t)255;
        return p;
    };
    int*   dflag   = (int*)  alloc(256);
    int*   iflag   = (int*)  alloc(256);
    int*   srcW    = (int*)  alloc((size_t)EE * 4);
    int*   dstW    = (int*)  alloc((size_t)EE * 4);
    float* out_f32 = (float*)alloc((size_t)NN * HH * 4);
    float* m_f32   = (float*)alloc((size_t)NN * HH * 4);
    float* ea_f32  = (float*)alloc((size_t)EE * EDD * 4);
    int*   counts  = (int*)  alloc((size_t)NN * 4);
    int*   offs    = (int*)  alloc((size_t)(NN + 1) * 4);
    int*   cursor  = (int*)  alloc((size_t)NN * 4);
    int*   eord    = (int*)  alloc((size_t)EE * 4);
    float* aggX    = (float*)alloc((size_t)NN * THD * 4);
    float* aggS    = (float*)alloc((size_t)NN * THD * 4);
    float* aggM    = (float*)alloc((size_t)NN * THD * 4);
    float* encWc  = (float*)alloc((size_t)24576 * 4);
    float* encbc  = (float*)alloc((size_t)384 * 4);
    float* preWc  = (float*)alloc((size_t)589824 * 4);
    float* prebc  = (float*)alloc((size_t)1536 * 4);
    float* postWc = (float*)alloc((size_t)196608 * 4);
    float* postbc = (float*)alloc((size_t)384 * 4);
    float* linWc  = (float*)alloc((size_t)49152 * 4);
    float* linbc  = (float*)alloc((size_t)384 * 4);
    float* Wihc   = (float*)alloc((size_t)49152 * 4);
    float* Whhc   = (float*)alloc((size_t)49152 * 4);
    float* bihc   = (float*)alloc((size_t)384 * 4);
    float* bhhc   = (float*)alloc((size_t)384 * 4);
    float* em1Wc  = (float*)alloc((size_t)65536 * 4);
    float* em1bc  = (float*)alloc((size_t)256 * 4);
    float* em2Wc  = (float*)alloc((size_t)32768 * 4);
    float* em2bc  = (float*)alloc((size_t)128 * 4);
    float* eu1Wc  = (float*)alloc((size_t)24576 * 4);
    float* eu1bc  = (float*)alloc((size_t)128 * 4);
    float* eu2Wc  = (float*)alloc((size_t)8192 * 4);
    float* eu2bc  = (float*)alloc((size_t)64 * 4);
    char*  region = alloc((size_t)52828160);
    bf16*  enc_e = (bf16*) (region);
    float* msg   = (float*)(region + 16777216);
    float* gi    = (float*)(region);
    float* gh    = (float*)(region + 6291456);
    float* SA    = (float*)(region);
    float* SB    = (float*)(region + 4194304);
    bf16*  cat   = (bf16*) (region + 8388608);
    bf16*  t2    = (bf16*) (region + 33554432);

    if (ws_size < off) {
        k_sentinel<<<2048, 256, 0, stream>>>((float*)d_out, 44.f);
        return;
    }

    // ---- edge_index canonicalize ----
    k_detidx<<<1, 64, 0, stream>>>(eidx, iflag);
    k_extidx<<<EE / 256, 256, 0, stream>>>(eidx, srcW, dstW, iflag);

    // ---- float canonicalize ----
    k_detect<<<1, 64, 0, stream>>>(d_in[1], dflag);
    auto CF = [&](int idx, float* dst, int n) {
        k_canon_f<<<(n + 255) / 256, 256, 0, stream>>>(d_in[idx], dst, n, dflag);
    };
    CF(3, encWc, 24576);      CF(4, encbc, 384);
    CF(5, preWc, 589824);     CF(6, prebc, 1536);
    CF(7, postWc, 196608);    CF(8, postbc, 384);
    CF(9, linWc, 49152);      CF(10, linbc, 384);
    CF(11, Wihc, 49152);      CF(12, Whhc, 49152);
    CF(13, bihc, 384);        CF(14, bhhc, 384);
    CF(15, em1Wc, 65536);     CF(16, em1bc, 256);
    CF(17, em2Wc, 32768);     CF(18, em2bc, 128);
    CF(19, eu1Wc, 24576);     CF(20, eu1bc, 128);
    CF(21, eu2Wc, 8192);      CF(22, eu2bc, 64);
    CF(0, out_f32, NN * HH);
    CF(1, ea_f32, EE * EDD);

    auto GEMM = [&](int amode, const void* A, int lda,
                    const float* sa, const float* sb, const float* b1,
                    const float* xn, const bf16* ee,
                    const float* Wm, int ldw, const float* bias,
                    void* C, int ldc, int M, int Nout, int K, bool relu, bool outbf) {
        dim3 grid(M / 64, Nout / 64);
#define LAUNCH(AM, RL, OB) k_vgemm<AM, RL, OB><<<grid, 256, 0, stream>>>( \
            A, lda, sa, sb, b1, xn, ee, srcW, dstW, Wm, ldw, bias, C, ldc, K)
        if (amode == 0) {
            if (relu) { if (outbf) LAUNCH(0, true, true); else LAUNCH(0, true, false); }
            else      { if (outbf) LAUNCH(0, false, true); else LAUNCH(0, false, false); }
        } else if (amode == 1) {
            if (relu) { if (outbf) LAUNCH(1, true, true); else LAUNCH(1, true, false); }
            else      { if (outbf) LAUNCH(1, false, true); else LAUNCH(1, false, false); }
        } else if (amode == 2) {
            if (relu) { if (outbf) LAUNCH(2, true, true); else LAUNCH(2, true, false); }
            else      { if (outbf) LAUNCH(2, false, true); else LAUNCH(2, false, false); }
        } else {
            if (relu) { if (outbf) LAUNCH(3, true, true); else LAUNCH(3, true, false); }
            else      { if (outbf) LAUNCH(3, false, true); else LAUNCH(3, false, false); }
        }
#undef LAUNCH
    };

    // ---- CSR ----
    hipMemsetAsync(counts, 0, NN * 4, stream);
    k_count<<<EE / 256, 256, 0, stream>>>(dstW, counts);
    k_scan<<<1, 1024, 0, stream>>>(counts, offs, cursor);
    k_fill<<<EE / 256, 256, 0, stream>>>(dstW, cursor, eord);

    for (int l = 0; l < 3; l++) {
        const float* preW_l  = preWc  + (size_t)l * 196608;
        const float* encW_l  = encWc  + (size_t)l * 8192;
        const float* encb_l  = encbc  + (size_t)l * 128;
        const float* preb_l  = prebc  + (size_t)l * 512;
        const float* postW_l = postWc + (size_t)l * 65536;
        const float* postb_l = postbc + (size_t)l * 128;
        const float* linW_l  = linWc  + (size_t)l * 16384;
        const float* linb_l  = linbc  + (size_t)l * 128;

        // ---- PNA (direct) ----
        GEMM(0, ea_f32, EDD, 0, 0, 0, 0, 0, encW_l, EDD, encb_l,
             enc_e, 128, EE, 128, EDD, false, true);
        for (int ts = 0; ts < 4; ts++) {
            GEMM(3, nullptr, 0, 0, 0, 0, out_f32, enc_e,
                 preW_l + (size_t)ts * 128 * 384, 384, preb_l + ts * 128,
                 msg, 128, EE, 128, 384, false, false);
            k_aggd<<<NN, 128, 0, stream>>>(msg, offs, eord, aggX, aggS, aggM, ts);
        }
        k_post<<<NN, 128, 0, stream>>>(out_f32, aggX, aggS, aggM,
                                       postW_l, postb_l, linW_l, linb_l, m_f32);
        // ---- GRU ----
        GEMM(0, m_f32,   HH, 0, 0, 0, 0, 0, Wihc, HH, bihc, gi, 384, NN, 384, HH, false, false);
        GEMM(0, out_f32, HH, 0, 0, 0, 0, 0, Whhc, HH, bhhc, gh, 384, NN, 384, HH, false, false);
        k_gru<<<NN * HH / 256, 256, 0, stream>>>(gi, gh, out_f32);
        // ---- edge update ----
        GEMM(0, out_f32, HH, 0, 0, 0, 0, 0, em1Wc,       256, nullptr, SA, 256, NN, 256, HH, false, false);
        GEMM(0, out_f32, HH, 0, 0, 0, 0, 0, em1Wc + 128, 256, nullptr, SB, 256, NN, 256, HH, false, false);
        GEMM(2, nullptr, 0, SA, SB, em1bc, 0, 0, em2Wc, 256, em2bc, cat, 192, EE, 128, 256, true, true);
        k_copy_ea<<<EE * EDD / 256, 256, 0, stream>>>(ea_f32, cat);
        GEMM(1, cat, 192, 0, 0, 0, 0, 0, eu1Wc, 192, eu1bc, t2,     128, EE, 128, 192, true, true);
        GEMM(1, t2,  128, 0, 0, 0, 0, 0, eu2Wc, 128, eu2bc, ea_f32, EDD, EE, 64,  128, false, false);
    }

    k_writeout<<<(2 * NN * HH + EE * EDD) / 256, 256, 0, stream>>>(out_f32, ea_f32, (float*)d_out);
}

// Round 8
// 931.683 us; speedup vs baseline: 3.3308x; 3.3308x over previous
//
#include <hip/hip_runtime.h>
#include <hip/hip_bf16.h>
#include <math.h>

#define NN 4096
#define EE 65536
#define HH 128
#define EDD 64
#define THD 512

typedef __bf16 bf16;
typedef __bf16 bf16x8 __attribute__((ext_vector_type(8)));
typedef float  floatx4 __attribute__((ext_vector_type(4)));

// ---------------------------------------------------------------------------
// input dtype detects (proven: floats are f32, edge_index is int32; kept as
// cheap insurance)
// ---------------------------------------------------------------------------
__global__ __launch_bounds__(64) void k_detect(const void* __restrict__ p,
                                               int* __restrict__ flag)
{
    const bf16* b = (const bf16*)p;
    int t = threadIdx.x;
    int bad = 0;
    for (int i = 0; i < 32; i++) {
        float v = (float)b[t * 32 + i];
        if (!(v == v) || fabsf(v) > 100.f) bad = 1;
    }
    unsigned long long m = __ballot(bad);
    if (t == 0) *flag = (m == 0ULL) ? 1 : 0;
}

__global__ void k_canon_f(const void* __restrict__ src, float* __restrict__ dst,
                          int n, const int* __restrict__ flag)
{
    int i = blockIdx.x * 256 + threadIdx.x;
    if (i >= n) return;
    dst[i] = (*flag) ? (float)((const bf16*)src)[i] : ((const float*)src)[i];
}

__global__ void k_canon_b(const void* __restrict__ src, bf16* __restrict__ dst,
                          int n, const int* __restrict__ flag)
{
    int i = blockIdx.x * 256 + threadIdx.x;
    if (i >= n) return;
    dst[i] = (*flag) ? ((const bf16*)src)[i] : (bf16)((const float*)src)[i];
}

__global__ void k_canon_fb(const void* __restrict__ src, float* __restrict__ dst,
                           bf16* __restrict__ dst2, int n, const int* __restrict__ flag)
{
    int i = blockIdx.x * 256 + threadIdx.x;
    if (i >= n) return;
    float v = (*flag) ? (float)((const bf16*)src)[i] : ((const float*)src)[i];
    dst[i] = v;
    dst2[i] = (bf16)v;
}

__global__ __launch_bounds__(64) void k_detidx(const int* __restrict__ p,
                                               int* __restrict__ iflag)
{
    int t = threadIdx.x;
    int bad = 0;
    for (int i = 0; i < 8; i++) {
        int k = t * 8 + i;
        int lo = p[2 * k], hi = p[2 * k + 1];
        if (hi != 0 || lo < 0 || lo >= NN) bad = 1;
    }
    unsigned long long m = __ballot(bad);
    if (t == 0) *iflag = (m == 0ULL) ? 1 : 0;
}

__global__ void k_extidx(const int* __restrict__ p, int* __restrict__ srcW,
                         int* __restrict__ dstW, const int* __restrict__ iflag)
{
    int e = blockIdx.x * 256 + threadIdx.x;
    int s, d;
    if (*iflag) { s = p[2 * e];  d = p[2 * EE + 2 * e]; }
    else        { s = p[e];      d = p[EE + e]; }
    srcW[e] = min(max(s, 0), NN - 1);
    dstW[e] = min(max(d, 0), NN - 1);
}

// ---------------------------------------------------------------------------
// MFMA bf16 GEMM: C[M,Nout] = act(A[M,K] @ W[Nout,K]^T + bias), f32 accumulate
// AMODE 0: A bf16 ; 1: A f32 (convert in staging) ;
//       2: A row e = relu(SA[src[e]] + SB[dst[e]] + b1)  (K=256)
// OM 0: C f32 ; 1: C bf16.
// grid=(M/64, Nout/64), block=256 (4 waves, 2x2 wave grid of 32x32, each 2x2
// 16x16x32 MFMA tiles). Fragment maps per HW-verified m89/m91 layouts.
// ---------------------------------------------------------------------------
template<int AMODE, bool RELU, int OM>
__global__ __launch_bounds__(256) void k_mgemm(
    const void* __restrict__ Av, int lda,
    const float* __restrict__ SA, const float* __restrict__ SB,
    const float* __restrict__ b1,
    const int* __restrict__ src, const int* __restrict__ dst,
    const bf16* __restrict__ W, int ldw, const float* __restrict__ bias,
    void* __restrict__ Cv, int ldc, int K)
{
    __shared__ bf16 As[64][40];
    __shared__ bf16 Ws[64][40];
    const int m0 = blockIdx.x * 64, n0 = blockIdx.y * 64;
    const int tid = threadIdx.x, wave = tid >> 6, lane = tid & 63;
    const int wm = (wave & 1) * 32, wn = (wave >> 1) * 32;
    const int lrow = tid >> 2, lcol = (tid & 3) * 8;
    const int fr = lane & 15, fk = (lane >> 4) * 8;
    floatx4 acc00 = {0,0,0,0}, acc01 = {0,0,0,0}, acc10 = {0,0,0,0}, acc11 = {0,0,0,0};

    int sI = 0, dI = 0;
    if (AMODE == 2) { sI = src[m0 + lrow]; dI = dst[m0 + lrow]; }

    for (int k0 = 0; k0 < K; k0 += 32) {
        bf16 a8[8];
        if (AMODE == 0) {
            const bf16* Ap = (const bf16*)Av + (size_t)(m0 + lrow) * lda + k0 + lcol;
            *(bf16x8*)a8 = *(const bf16x8*)Ap;
        } else if (AMODE == 1) {
            const float* Ap = (const float*)Av + (size_t)(m0 + lrow) * lda + k0 + lcol;
#pragma unroll
            for (int j = 0; j < 8; j++) a8[j] = (bf16)Ap[j];
        } else {
#pragma unroll
            for (int j = 0; j < 8; j++) {
                int c = k0 + lcol + j;
                a8[j] = (bf16)fmaxf(SA[(size_t)sI * 256 + c] + SB[(size_t)dI * 256 + c] + b1[c], 0.f);
            }
        }
        bf16 w8[8];
        {
            const bf16* Wp = W + (size_t)(n0 + lrow) * ldw + k0 + lcol;
            *(bf16x8*)w8 = *(const bf16x8*)Wp;
        }
        __syncthreads();
        *(bf16x8*)&As[lrow][lcol] = *(bf16x8*)a8;
        *(bf16x8*)&Ws[lrow][lcol] = *(bf16x8*)w8;
        __syncthreads();
        bf16x8 a0 = *(const bf16x8*)&As[wm + fr][fk];
        bf16x8 a1 = *(const bf16x8*)&As[wm + 16 + fr][fk];
        bf16x8 b0 = *(const bf16x8*)&Ws[wn + fr][fk];
        bf16x8 b1v = *(const bf16x8*)&Ws[wn + 16 + fr][fk];
        acc00 = __builtin_amdgcn_mfma_f32_16x16x32_bf16(a0, b0, acc00, 0, 0, 0);
        acc01 = __builtin_amdgcn_mfma_f32_16x16x32_bf16(a0, b1v, acc01, 0, 0, 0);
        acc10 = __builtin_amdgcn_mfma_f32_16x16x32_bf16(a1, b0, acc10, 0, 0, 0);
        acc11 = __builtin_amdgcn_mfma_f32_16x16x32_bf16(a1, b1v, acc11, 0, 0, 0);
    }
    const int cc = lane & 15, cr = (lane >> 4) * 4;
    float vb0 = bias ? bias[n0 + wn + cc] : 0.f;
    float vb1 = bias ? bias[n0 + wn + 16 + cc] : 0.f;
    floatx4 accs[2][2] = {{acc00, acc01}, {acc10, acc11}};
#pragma unroll
    for (int mt = 0; mt < 2; mt++)
#pragma unroll
        for (int nt = 0; nt < 2; nt++) {
            float vb = nt ? vb1 : vb0;
#pragma unroll
            for (int i = 0; i < 4; i++) {
                int gm = m0 + wm + mt * 16 + cr + i;
                int gn = n0 + wn + nt * 16 + cc;
                float v = accs[mt][nt][i] + vb;
                if (RELU) v = fmaxf(v, 0.f);
                if (OM == 1) ((bf16*)Cv)[(size_t)gm * ldc + gn] = (bf16)v;
                else         ((float*)Cv)[(size_t)gm * ldc + gn] = v;
            }
        }
}

// ---------------------------------------------------------------------------
// Post-MLP as per-tower MFMA GEMM: y[n, t*32+f] = cat_t[n,:512] . qW[t*32+f,:]
// grid=(N/64, T), block=256. A rows built on the fly from x|aggX|aggS|aggM.
// No activation (reference applies none before lin).
// ---------------------------------------------------------------------------
__global__ __launch_bounds__(256) void k_postg(
    const float* __restrict__ xin, const float* __restrict__ aggX,
    const float* __restrict__ aggS, const float* __restrict__ aggM,
    const bf16* __restrict__ qWbf, const float* __restrict__ qb,
    bf16* __restrict__ ybf)
{
    __shared__ bf16 As[64][40];
    __shared__ bf16 Ws[32][40];
    const int n0 = blockIdx.x * 64, t = blockIdx.y;
    const int tid = threadIdx.x, wave = tid >> 6, lane = tid & 63;
    const int lrow = tid >> 2, lcol = (tid & 3) * 8;
    const int fr = lane & 15, fk = (lane >> 4) * 8;
    floatx4 acc0 = {0,0,0,0}, acc1 = {0,0,0,0};

    for (int k0 = 0; k0 < 512; k0 += 32) {
        int n = n0 + lrow;
        int c0 = k0 + lcol;
        const float* srcp;
        if (c0 < 128)      srcp = xin  + (size_t)n * 128 + c0;
        else if (c0 < 256) srcp = aggX + (size_t)n * 512 + t * 128 + (c0 - 128);
        else if (c0 < 384) srcp = aggS + (size_t)n * 512 + t * 128 + (c0 - 256);
        else               srcp = aggM + (size_t)n * 512 + t * 128 + (c0 - 384);
        bf16 a8[8];
#pragma unroll
        for (int j = 0; j < 8; j++) a8[j] = (bf16)srcp[j];
        bf16 w8[8];
        if (tid < 128) {
            int wr = tid >> 2, wc = (tid & 3) * 8;
            *(bf16x8*)w8 = *(const bf16x8*)(qWbf + (size_t)(t * 32 + wr) * 512 + k0 + wc);
        }
        __syncthreads();
        *(bf16x8*)&As[lrow][lcol] = *(bf16x8*)a8;
        if (tid < 128) {
            int wr = tid >> 2, wc = (tid & 3) * 8;
            *(bf16x8*)&Ws[wr][wc] = *(bf16x8*)w8;
        }
        __syncthreads();
        bf16x8 a  = *(const bf16x8*)&As[wave * 16 + fr][fk];
        bf16x8 b0 = *(const bf16x8*)&Ws[fr][fk];
        bf16x8 b1 = *(const bf16x8*)&Ws[16 + fr][fk];
        acc0 = __builtin_amdgcn_mfma_f32_16x16x32_bf16(a, b0, acc0, 0, 0, 0);
        acc1 = __builtin_amdgcn_mfma_f32_16x16x32_bf16(a, b1, acc1, 0, 0, 0);
    }
    const int cc = lane & 15, cr = (lane >> 4) * 4;
#pragma unroll
    for (int i = 0; i < 4; i++) {
        int gn = n0 + wave * 16 + cr + i;
        ybf[(size_t)gn * 128 + t * 32 + cc]      = (bf16)(acc0[i] + qb[t * 32 + cc]);
        ybf[(size_t)gn * 128 + t * 32 + 16 + cc] = (bf16)(acc1[i] + qb[t * 32 + 16 + cc]);
    }
}

// ---------------------------------------------------------------------------
// Fold edge-encoder into pre-MLP: wcomb[tf,d] = sum_h preW[tf,256+h]*encW[h,d]
// (bf16 out), bcomb[tf] = sum_h preW[tf,256+h]*encb[h] + preb[tf] (f32).
// ---------------------------------------------------------------------------
__global__ __launch_bounds__(64) void k_wcomb(
    const float* __restrict__ preW, const float* __restrict__ encW,
    const float* __restrict__ encb, const float* __restrict__ preb,
    bf16* __restrict__ wcomb, float* __restrict__ bcomb)
{
    int tf = blockIdx.x, d = threadIdx.x;
    __shared__ float pw[128];
    __shared__ float red[64];
    const float* pr = preW + (size_t)tf * 384 + 256;
    pw[d]      = pr[d];
    pw[d + 64] = pr[d + 64];
    __syncthreads();
    float acc = 0.f;
    for (int h = 0; h < 128; h++) acc += pw[h] * encW[h * 64 + d];
    wcomb[tf * 64 + d] = (bf16)acc;
    float b = pw[d] * encb[d] + pw[d + 64] * encb[d + 64];
    red[d] = b;
    __syncthreads();
    for (int s = 32; s > 0; s >>= 1) { if (d < s) red[d] += red[d + s]; __syncthreads(); }
    if (d == 0) bcomb[tf] = red[0] + preb[tf];
}

// ----------------------- CSR build -----------------------------------------
__global__ void k_count(const int* __restrict__ dst, int* __restrict__ counts)
{
    int e = blockIdx.x * 256 + threadIdx.x;
    atomicAdd(&counts[dst[e]], 1);
}

__global__ __launch_bounds__(1024) void k_scan(
    const int* __restrict__ counts, int* __restrict__ offs, int* __restrict__ cursor)
{
    __shared__ int ls[1024];
    int tid = threadIdx.x, base = tid * 4;
    int c0 = counts[base], c1 = counts[base + 1], c2 = counts[base + 2], c3 = counts[base + 3];
    ls[tid] = c0 + c1 + c2 + c3;
    __syncthreads();
    for (int d = 1; d < 1024; d <<= 1) {
        int v = (tid >= d) ? ls[tid - d] : 0;
        __syncthreads();
        ls[tid] += v;
        __syncthreads();
    }
    int r = tid ? ls[tid - 1] : 0;
    offs[base] = r;     cursor[base] = r;     r += c0;
    offs[base + 1] = r; cursor[base + 1] = r; r += c1;
    offs[base + 2] = r; cursor[base + 2] = r; r += c2;
    offs[base + 3] = r; cursor[base + 3] = r; r += c3;
    if (tid == 1023) offs[4096] = r;
}

__global__ void k_fill(const int* __restrict__ dst, int* __restrict__ cursor,
                       int* __restrict__ eord)
{
    int e = blockIdx.x * 256 + threadIdx.x;
    int p = atomicAdd(&cursor[dst[e]], 1);
    eord[p] = e;
}

// ---------------------------------------------------------------------------
// Factored aggregation (tower-slice ts): msg = Pd[n]+bcomb + Ps[src] + Q[e]
// -> mean/std/masked-max into agg*[n, ts*128+tid]. grid=N, block=128.
// ---------------------------------------------------------------------------
__global__ __launch_bounds__(128) void k_agg(
    const float* __restrict__ Pd, const float* __restrict__ Ps,
    const bf16* __restrict__ Q, const float* __restrict__ bcomb,
    const int* __restrict__ src, const int* __restrict__ offs,
    const int* __restrict__ eord,
    float* __restrict__ aggX, float* __restrict__ aggS, float* __restrict__ aggM,
    int ts)
{
    int n = blockIdx.x, tid = threadIdx.x;
    float p = Pd[(size_t)n * 128 + tid] + bcomb[ts * 128 + tid];
    float s = 0.f, q = 0.f, x = -3e38f;
    int beg = offs[n], end = offs[n + 1];
    for (int i = beg; i < end; i++) {
        int e = eord[i];
        int sn = src[e];
        float m = p + Ps[(size_t)sn * 128 + tid] + (float)Q[(size_t)e * 128 + tid];
        s += m; q += m * m; x = fmaxf(x, m);
    }
    int cnt = end - beg;
    float inv = 1.f / fmaxf((float)cnt, 1.f);
    float me = s * inv;
    float v = fmaxf(q * inv - me * me, 0.f);
    size_t o = (size_t)n * THD + ts * 128 + tid;
    aggX[o] = cnt > 0 ? x : 0.f;
    aggS[o] = sqrtf(v + 1e-5f);
    aggM[o] = me;
}

// --------------------------- GRU elementwise --------------------------------
__global__ void k_gru(const float* __restrict__ gi, const float* __restrict__ gh,
                      float* __restrict__ hst, bf16* __restrict__ ob)
{
    int i = blockIdx.x * 256 + threadIdx.x;
    int k = i & 127;
    size_t b = (size_t)(i >> 7) * 384;
    float ir = gi[b + k],       hr = gh[b + k];
    float iz = gi[b + 128 + k], hz = gh[b + 128 + k];
    float ic = gi[b + 256 + k], hc = gh[b + 256 + k];
    float r = 1.f / (1.f + __expf(-(ir + hr)));
    float z = 1.f / (1.f + __expf(-(iz + hz)));
    float c = tanhf(ic + r * hc);
    float h = hst[i];
    float hn = (1.f - z) * c + z * h;
    hst[i] = hn;
    ob[i] = (bf16)hn;
}

__global__ void k_copy_ea(const float* __restrict__ ea, bf16* __restrict__ cat)
{
    int i = blockIdx.x * 256 + threadIdx.x;
    int e = i >> 6, d = i & 63;
    cat[(size_t)e * 192 + 128 + d] = (bf16)ea[i];
}

__global__ void k_writeout(const float* __restrict__ of, const float* __restrict__ ea,
                           float* __restrict__ o)
{
    size_t i = (size_t)blockIdx.x * 256 + threadIdx.x;
    if (i < 524288)            o[i] = of[i];
    else if (i < 4718592)      o[i] = ea[i - 524288];
    else                       o[i] = of[i - 4718592];
}

__global__ void k_sentinel(float* __restrict__ o, float v)
{
    int i = blockIdx.x * 256 + threadIdx.x;
    o[i] = v;
}

// ===========================================================================
extern "C" void kernel_launch(void* const* d_in, const int* in_sizes, int n_in,
                              void* d_out, int out_size, void* d_ws, size_t ws_size,
                              hipStream_t stream)
{
    static const int exp_sizes[23] = {
        524288, 4194304, 131072, 24576, 384, 589824, 1536, 196608, 384,
        49152, 384, 49152, 49152, 384, 384, 65536, 256, 32768, 128,
        24576, 128, 8192, 64 };
    if (n_in != 23) { k_sentinel<<<2048, 256, 0, stream>>>((float*)d_out, 200.f); return; }
    for (int i = 0; i < 23; i++)
        if (in_sizes[i] != exp_sizes[i]) {
            k_sentinel<<<2048, 256, 0, stream>>>((float*)d_out, 60.f + 4.f * i);
            return;
        }
    if (out_size != 5242880) { k_sentinel<<<2048, 256, 0, stream>>>((float*)d_out, 52.f); return; }

    const int* eidx = (const int*)d_in[2];

    char* w = (char*)d_ws;
    size_t off = 0;
    auto alloc = [&](size_t bytes) -> char* {
        char* p = w + off;
        off = (off + bytes + 255) & ~(size_t)255;
        return p;
    };
    int*   dflag   = (int*)  alloc(256);
    int*   iflag   = (int*)  alloc(256);
    int*   srcW    = (int*)  alloc((size_t)EE * 4);
    int*   dstW    = (int*)  alloc((size_t)EE * 4);
    float* out_f32 = (float*)alloc((size_t)NN * HH * 4);
    bf16*  out_bf  = (bf16*) alloc((size_t)NN * HH * 2);
    bf16*  m_bf    = (bf16*) alloc((size_t)NN * HH * 2);
    bf16*  ybf     = (bf16*) alloc((size_t)NN * HH * 2);
    float* ea_f32  = (float*)alloc((size_t)EE * EDD * 4);
    bf16*  wcombBf = (bf16*) alloc((size_t)THD * EDD * 2);
    float* bcomb   = (float*)alloc((size_t)THD * 4);
    int*   counts  = (int*)  alloc((size_t)NN * 4);
    int*   offs    = (int*)  alloc((size_t)(NN + 1) * 4);
    int*   cursor  = (int*)  alloc((size_t)NN * 4);
    int*   eord    = (int*)  alloc((size_t)EE * 4);
    float* aggX    = (float*)alloc((size_t)NN * THD * 4);
    float* aggS    = (float*)alloc((size_t)NN * THD * 4);
    float* aggM    = (float*)alloc((size_t)NN * THD * 4);
    // f32 weights needed for folding / biases
    float* encWc  = (float*)alloc((size_t)24576 * 4);
    float* encbc  = (float*)alloc((size_t)384 * 4);
    float* preWc  = (float*)alloc((size_t)589824 * 4);
    float* prebc  = (float*)alloc((size_t)1536 * 4);
    float* postbc = (float*)alloc((size_t)384 * 4);
    float* linbc  = (float*)alloc((size_t)384 * 4);
    float* bihc   = (float*)alloc((size_t)384 * 4);
    float* bhhc   = (float*)alloc((size_t)384 * 4);
    float* em1bc  = (float*)alloc((size_t)256 * 4);
    float* em2bc  = (float*)alloc((size_t)128 * 4);
    float* eu1bc  = (float*)alloc((size_t)128 * 4);
    float* eu2bc  = (float*)alloc((size_t)64 * 4);
    // bf16 GEMM weights
    bf16* preWbf = (bf16*)alloc((size_t)589824 * 2);
    bf16* postWbf= (bf16*)alloc((size_t)196608 * 2);
    bf16* linWbf = (bf16*)alloc((size_t)49152 * 2);
    bf16* WihBf  = (bf16*)alloc((size_t)49152 * 2);
    bf16* WhhBf  = (bf16*)alloc((size_t)49152 * 2);
    bf16* em1Wbf = (bf16*)alloc((size_t)65536 * 2);
    bf16* em2Wbf = (bf16*)alloc((size_t)32768 * 2);
    bf16* eu1Wbf = (bf16*)alloc((size_t)24576 * 2);
    bf16* eu2Wbf = (bf16*)alloc((size_t)8192 * 2);
    // phase-shared region (50.4 MB)
    char* region = alloc((size_t)50331648);
    // Phase PNA: Pds/Pss f32 [N,128], Qs bf16 [E,128]
    float* Pds = (float*)(region);
    float* Pss = (float*)(region + 2097152);
    bf16*  Qs  = (bf16*) (region + 4194304);            // 16.78 MB
    // Phase GRU:
    float* gi  = (float*)(region);                      // [N,384]
    float* gh  = (float*)(region + 6291456);
    // Phase edge:
    float* SA  = (float*)(region);                      // [N,256]
    float* SB  = (float*)(region + 4194304);
    bf16*  cat = (bf16*) (region + 8388608);            // [E,192]
    bf16*  t2  = (bf16*) (region + 33554432);           // [E,128]

    if (ws_size < off) { k_sentinel<<<2048, 256, 0, stream>>>((float*)d_out, 44.f); return; }

    // ---- canonicalize ----
    k_detidx<<<1, 64, 0, stream>>>(eidx, iflag);
    k_extidx<<<EE / 256, 256, 0, stream>>>(eidx, srcW, dstW, iflag);
    k_detect<<<1, 64, 0, stream>>>(d_in[1], dflag);
    auto CF = [&](int idx, float* dst, int n) {
        k_canon_f<<<(n + 255) / 256, 256, 0, stream>>>(d_in[idx], dst, n, dflag);
    };
    auto CB = [&](int idx, bf16* dst, int n) {
        k_canon_b<<<(n + 255) / 256, 256, 0, stream>>>(d_in[idx], dst, n, dflag);
    };
    k_canon_fb<<<(NN * HH + 255) / 256, 256, 0, stream>>>(d_in[0], out_f32, out_bf, NN * HH, dflag);
    k_canon_fb<<<(589824 + 255) / 256, 256, 0, stream>>>(d_in[5], preWc, preWbf, 589824, dflag);
    CF(1, ea_f32, EE * EDD);
    CF(3, encWc, 24576);   CF(4, encbc, 384);   CF(6, prebc, 1536);
    CF(8, postbc, 384);    CF(10, linbc, 384);  CF(13, bihc, 384);  CF(14, bhhc, 384);
    CF(16, em1bc, 256);    CF(18, em2bc, 128);  CF(20, eu1bc, 128); CF(22, eu2bc, 64);
    CB(7, postWbf, 196608); CB(9, linWbf, 49152);
    CB(11, WihBf, 49152);   CB(12, WhhBf, 49152);
    CB(15, em1Wbf, 65536);  CB(17, em2Wbf, 32768);
    CB(19, eu1Wbf, 24576);  CB(21, eu2Wbf, 8192);

    auto GEMM = [&](int amode, const void* A, int lda,
                    const float* sa, const float* sb, const float* b1,
                    const bf16* Wm, int ldw, const float* bias,
                    void* C, int ldc, int M, int Nout, int K, bool relu, int om) {
        dim3 grid(M / 64, Nout / 64);
#define LAUNCH(AM, RL, O) k_mgemm<AM, RL, O><<<grid, 256, 0, stream>>>( \
            A, lda, sa, sb, b1, srcW, dstW, Wm, ldw, bias, C, ldc, K)
        if (amode == 0) {
            if (relu) { if (om) LAUNCH(0, true, 1); else LAUNCH(0, true, 0); }
            else      { if (om) LAUNCH(0, false, 1); else LAUNCH(0, false, 0); }
        } else if (amode == 1) {
            if (relu) { if (om) LAUNCH(1, true, 1); else LAUNCH(1, true, 0); }
            else      { if (om) LAUNCH(1, false, 1); else LAUNCH(1, false, 0); }
        } else {
            if (relu) { if (om) LAUNCH(2, true, 1); else LAUNCH(2, true, 0); }
            else      { if (om) LAUNCH(2, false, 1); else LAUNCH(2, false, 0); }
        }
#undef LAUNCH
    };

    // ---- CSR ----
    hipMemsetAsync(counts, 0, NN * 4, stream);
    k_count<<<EE / 256, 256, 0, stream>>>(dstW, counts);
    k_scan<<<1, 1024, 0, stream>>>(counts, offs, cursor);
    k_fill<<<EE / 256, 256, 0, stream>>>(dstW, cursor, eord);

    for (int l = 0; l < 3; l++) {
        const float* preW_l  = preWc  + (size_t)l * 196608;
        const bf16*  preWbf_l= preWbf + (size_t)l * 196608;
        const float* encW_l  = encWc  + (size_t)l * 8192;
        const float* encb_l  = encbc  + (size_t)l * 128;
        const float* preb_l  = prebc  + (size_t)l * 512;
        const bf16*  postW_l = postWbf + (size_t)l * 65536;
        const float* postb_l = postbc + (size_t)l * 128;
        const bf16*  linW_l  = linWbf + (size_t)l * 16384;
        const float* linb_l  = linbc  + (size_t)l * 128;

        // ---- PNA (factored, per tower-slice) ----
        k_wcomb<<<THD, 64, 0, stream>>>(preW_l, encW_l, encb_l, preb_l, wcombBf, bcomb);
        for (int ts = 0; ts < 4; ts++) {
            const bf16* pWs = preWbf_l + (size_t)ts * 128 * 384;
            GEMM(0, out_bf, HH, 0, 0, 0, pWs,       384, nullptr, Pds, 128, NN, 128, HH, false, 0);
            GEMM(0, out_bf, HH, 0, 0, 0, pWs + 128, 384, nullptr, Pss, 128, NN, 128, HH, false, 0);
            GEMM(1, ea_f32, EDD, 0, 0, 0, wcombBf + (size_t)ts * 128 * 64, EDD, nullptr,
                 Qs, 128, EE, 128, EDD, false, 1);
            k_agg<<<NN, 128, 0, stream>>>(Pds, Pss, Qs, bcomb, srcW, offs, eord,
                                          aggX, aggS, aggM, ts);
        }
        k_postg<<<dim3(NN / 64, 4), 256, 0, stream>>>(out_f32, aggX, aggS, aggM,
                                                      postW_l, postb_l, ybf);
        GEMM(0, ybf, HH, 0, 0, 0, linW_l, HH, linb_l, m_bf, HH, NN, HH, HH, true, 1);
        // ---- GRU ----
        GEMM(0, m_bf,   HH, 0, 0, 0, WihBf, HH, bihc, gi, 384, NN, 384, HH, false, 0);
        GEMM(0, out_bf, HH, 0, 0, 0, WhhBf, HH, bhhc, gh, 384, NN, 384, HH, false, 0);
        k_gru<<<NN * HH / 256, 256, 0, stream>>>(gi, gh, out_f32, out_bf);
        // ---- edge update ----
        GEMM(0, out_bf, HH, 0, 0, 0, em1Wbf,       256, nullptr, SA, 256, NN, 256, HH, false, 0);
        GEMM(0, out_bf, HH, 0, 0, 0, em1Wbf + 128, 256, nullptr, SB, 256, NN, 256, HH, false, 0);
        GEMM(2, nullptr, 0, SA, SB, em1bc, em2Wbf, 256, em2bc, cat, 192, EE, 128, 256, true, 1);
        k_copy_ea<<<EE * EDD / 256, 256, 0, stream>>>(ea_f32, cat);
        GEMM(0, cat, 192, 0, 0, 0, eu1Wbf, 192, eu1bc, t2,     128, EE, 128, 192, true, 1);
        GEMM(0, t2,  128, 0, 0, 0, eu2Wbf, 128, eu2bc, ea_f32, EDD, EE, 64,  128, false, 0);
    }

    k_writeout<<<(2 * NN * HH + EE * EDD) / 256, 256, 0, stream>>>(out_f32, ea_f32, (float*)d_out);
}

// Round 9
// 659.060 us; speedup vs baseline: 4.7085x; 1.4137x over previous
//
#include <hip/hip_runtime.h>
#include <hip/hip_bf16.h>
#include <math.h>

#define NN 4096
#define EE 65536
#define HH 128
#define EDD 64
#define THD 512

typedef __bf16 bf16;
typedef __bf16 bf16x8 __attribute__((ext_vector_type(8)));
typedef __bf16 bf16x2 __attribute__((ext_vector_type(2)));
typedef float  floatx4 __attribute__((ext_vector_type(4)));

// ---------------------------------------------------------------------------
// input dtype detects (proven: floats f32, edge_index int32; cheap insurance)
// ---------------------------------------------------------------------------
__global__ __launch_bounds__(64) void k_detect(const void* __restrict__ p,
                                               int* __restrict__ flag)
{
    const bf16* b = (const bf16*)p;
    int t = threadIdx.x;
    int bad = 0;
    for (int i = 0; i < 32; i++) {
        float v = (float)b[t * 32 + i];
        if (!(v == v) || fabsf(v) > 100.f) bad = 1;
    }
    unsigned long long m = __ballot(bad);
    if (t == 0) *flag = (m == 0ULL) ? 1 : 0;
}

__global__ void k_canon_f(const void* __restrict__ src, float* __restrict__ dst,
                          int n, const int* __restrict__ flag)
{
    int i = blockIdx.x * 256 + threadIdx.x;
    if (i >= n) return;
    dst[i] = (*flag) ? (float)((const bf16*)src)[i] : ((const float*)src)[i];
}

__global__ void k_canon_b(const void* __restrict__ src, bf16* __restrict__ dst,
                          int n, const int* __restrict__ flag)
{
    int i = blockIdx.x * 256 + threadIdx.x;
    if (i >= n) return;
    dst[i] = (*flag) ? ((const bf16*)src)[i] : (bf16)((const float*)src)[i];
}

__global__ void k_canon_fb(const void* __restrict__ src, float* __restrict__ dst,
                           bf16* __restrict__ dst2, int n, const int* __restrict__ flag)
{
    int i = blockIdx.x * 256 + threadIdx.x;
    if (i >= n) return;
    float v = (*flag) ? (float)((const bf16*)src)[i] : ((const float*)src)[i];
    dst[i] = v;
    dst2[i] = (bf16)v;
}

__global__ __launch_bounds__(64) void k_detidx(const int* __restrict__ p,
                                               int* __restrict__ iflag)
{
    int t = threadIdx.x;
    int bad = 0;
    for (int i = 0; i < 8; i++) {
        int k = t * 8 + i;
        int lo = p[2 * k], hi = p[2 * k + 1];
        if (hi != 0 || lo < 0 || lo >= NN) bad = 1;
    }
    unsigned long long m = __ballot(bad);
    if (t == 0) *iflag = (m == 0ULL) ? 1 : 0;
}

__global__ void k_extidx(const int* __restrict__ p, int* __restrict__ srcW,
                         int* __restrict__ dstW, const int* __restrict__ iflag)
{
    int e = blockIdx.x * 256 + threadIdx.x;
    int s, d;
    if (*iflag) { s = p[2 * e];  d = p[2 * EE + 2 * e]; }
    else        { s = p[e];      d = p[EE + e]; }
    srcW[e] = min(max(s, 0), NN - 1);
    dstW[e] = min(max(d, 0), NN - 1);
}

// ---------------------------------------------------------------------------
// MFMA bf16 GEMM: C[M,Nout] = act(A[M,K](bf16) @ W[Nout,K]^T(bf16) + bias)
// OM 0: C f32 ; 1: C bf16. grid=(M/64, Nout/64), block=256 (4 waves, 2x2 of
// 32x32, each 2x2 16x16x32 MFMAs). Validated green in R8.
// ---------------------------------------------------------------------------
template<bool RELU, int OM>
__global__ __launch_bounds__(256) void k_mgemm(
    const bf16* __restrict__ A, int lda,
    const bf16* __restrict__ W, int ldw, const float* __restrict__ bias,
    void* __restrict__ Cv, int ldc, int K)
{
    __shared__ bf16 As[64][40];
    __shared__ bf16 Ws[64][40];
    const int m0 = blockIdx.x * 64, n0 = blockIdx.y * 64;
    const int tid = threadIdx.x, wave = tid >> 6, lane = tid & 63;
    const int wm = (wave & 1) * 32, wn = (wave >> 1) * 32;
    const int lrow = tid >> 2, lcol = (tid & 3) * 8;
    const int fr = lane & 15, fk = (lane >> 4) * 8;
    floatx4 acc00 = {0,0,0,0}, acc01 = {0,0,0,0}, acc10 = {0,0,0,0}, acc11 = {0,0,0,0};

    for (int k0 = 0; k0 < K; k0 += 32) {
        bf16x8 av = *(const bf16x8*)(A + (size_t)(m0 + lrow) * lda + k0 + lcol);
        bf16x8 wv = *(const bf16x8*)(W + (size_t)(n0 + lrow) * ldw + k0 + lcol);
        __syncthreads();
        *(bf16x8*)&As[lrow][lcol] = av;
        *(bf16x8*)&Ws[lrow][lcol] = wv;
        __syncthreads();
        bf16x8 a0 = *(const bf16x8*)&As[wm + fr][fk];
        bf16x8 a1 = *(const bf16x8*)&As[wm + 16 + fr][fk];
        bf16x8 b0 = *(const bf16x8*)&Ws[wn + fr][fk];
        bf16x8 b1 = *(const bf16x8*)&Ws[wn + 16 + fr][fk];
        acc00 = __builtin_amdgcn_mfma_f32_16x16x32_bf16(a0, b0, acc00, 0, 0, 0);
        acc01 = __builtin_amdgcn_mfma_f32_16x16x32_bf16(a0, b1, acc01, 0, 0, 0);
        acc10 = __builtin_amdgcn_mfma_f32_16x16x32_bf16(a1, b0, acc10, 0, 0, 0);
        acc11 = __builtin_amdgcn_mfma_f32_16x16x32_bf16(a1, b1, acc11, 0, 0, 0);
    }
    const int cc = lane & 15, cr = (lane >> 4) * 4;
    float vb0 = bias ? bias[n0 + wn + cc] : 0.f;
    float vb1 = bias ? bias[n0 + wn + 16 + cc] : 0.f;
    floatx4 accs[2][2] = {{acc00, acc01}, {acc10, acc11}};
#pragma unroll
    for (int mt = 0; mt < 2; mt++)
#pragma unroll
        for (int nt = 0; nt < 2; nt++) {
            float vb = nt ? vb1 : vb0;
#pragma unroll
            for (int i = 0; i < 4; i++) {
                int gm = m0 + wm + mt * 16 + cr + i;
                int gn = n0 + wn + nt * 16 + cc;
                float v = accs[mt][nt][i] + vb;
                if (RELU) v = fmaxf(v, 0.f);
                if (OM == 1) ((bf16*)Cv)[(size_t)gm * ldc + gn] = (bf16)v;
                else         ((float*)Cv)[(size_t)gm * ldc + gn] = v;
            }
        }
}

// ---------------------------------------------------------------------------
// Fused edge update: per 64-edge tile,
//   t1   = relu(SA[src] + SB[dst])                      (em1b folded into SA)
//   m_ed = relu(t1 @ em2W^T + em2b)         [64x128]  -> LDS
//   t2   = relu([m_ed | ea] @ eu1W^T + eu1b)[64x128]  -> LDS
//   ea'  = t2 @ eu2W^T + eu2b               [64x64]   -> global (f32 + bf16)
// grid=1024, block=256 (4 waves). In-place safe: each block owns its 64 rows.
// ---------------------------------------------------------------------------
__global__ __launch_bounds__(256) void k_edge(
    const float* __restrict__ SA, const float* __restrict__ SB,
    const bf16* __restrict__ em2W, const float* __restrict__ em2b,
    const bf16* __restrict__ eu1W, const float* __restrict__ eu1b,
    const bf16* __restrict__ eu2W, const float* __restrict__ eu2b,
    const int* __restrict__ src, const int* __restrict__ dst,
    const bf16* __restrict__ ea_in,
    float* __restrict__ ea_out_f, bf16* __restrict__ ea_out_b)
{
    __shared__ bf16 Ws[128][40];
    __shared__ bf16 As[64][40];
    __shared__ bf16 med[64][200];   // cols 0..127 m_ed, 128..191 ea
    __shared__ bf16 t2s[64][136];
    const int e0 = blockIdx.x * 64;
    const int tid = threadIdx.x, wave = tid >> 6, lane = tid & 63;
    const int lrow = tid >> 2, lcol = (tid & 3) * 8;
    const int fr = lane & 15, fk = (lane >> 4) * 8;
    const int cc = lane & 15, cr = (lane >> 4) * 4;
    const int sI = src[e0 + lrow], dI = dst[e0 + lrow];
    const floatx4 z4 = {0.f, 0.f, 0.f, 0.f};

    // ---------- stage 1: m_ed (out 64x128; wave = 32 rows x 64 cols) ----------
    const int wm1 = (wave & 1) * 32, wn1 = (wave >> 1) * 64;
    floatx4 acc1[2][4];
#pragma unroll
    for (int mt = 0; mt < 2; mt++)
#pragma unroll
        for (int nt = 0; nt < 4; nt++) acc1[mt][nt] = z4;

    for (int k0 = 0; k0 < 256; k0 += 32) {
        bf16 a8[8];
#pragma unroll
        for (int j = 0; j < 8; j++) {
            int c = k0 + lcol + j;
            a8[j] = (bf16)fmaxf(SA[(size_t)sI * 256 + c] + SB[(size_t)dI * 256 + c], 0.f);
        }
        int wr = tid & 127, wc = (tid >> 7) * 16;
        bf16x8 w0 = *(const bf16x8*)(em2W + (size_t)wr * 256 + k0 + wc);
        bf16x8 w1 = *(const bf16x8*)(em2W + (size_t)wr * 256 + k0 + wc + 8);
        __syncthreads();
        *(bf16x8*)&As[lrow][lcol] = *(bf16x8*)a8;
        *(bf16x8*)&Ws[wr][wc]     = w0;
        *(bf16x8*)&Ws[wr][wc + 8] = w1;
        __syncthreads();
        bf16x8 af[2], bv[4];
#pragma unroll
        for (int mt = 0; mt < 2; mt++) af[mt] = *(const bf16x8*)&As[wm1 + mt * 16 + fr][fk];
#pragma unroll
        for (int nt = 0; nt < 4; nt++) bv[nt] = *(const bf16x8*)&Ws[wn1 + nt * 16 + fr][fk];
#pragma unroll
        for (int mt = 0; mt < 2; mt++)
#pragma unroll
            for (int nt = 0; nt < 4; nt++)
                acc1[mt][nt] = __builtin_amdgcn_mfma_f32_16x16x32_bf16(af[mt], bv[nt], acc1[mt][nt], 0, 0, 0);
    }
#pragma unroll
    for (int mt = 0; mt < 2; mt++)
#pragma unroll
        for (int nt = 0; nt < 4; nt++)
#pragma unroll
            for (int i = 0; i < 4; i++) {
                int row = wm1 + mt * 16 + cr + i;
                int col = wn1 + nt * 16 + cc;
                med[row][col] = (bf16)fmaxf(acc1[mt][nt][i] + em2b[col], 0.f);
            }
    // append ea tile (cols 128..191)
    {
        int r = tid >> 2, c0 = (tid & 3) * 16;
        bf16x8 v0 = *(const bf16x8*)(ea_in + (size_t)(e0 + r) * 64 + c0);
        bf16x8 v1 = *(const bf16x8*)(ea_in + (size_t)(e0 + r) * 64 + c0 + 8);
        *(bf16x8*)&med[r][128 + c0]     = v0;
        *(bf16x8*)&med[r][128 + c0 + 8] = v1;
    }

    // ---------- stage 2: t2 (out 64x128, K=192) ----------
    floatx4 acc2[2][4];
#pragma unroll
    for (int mt = 0; mt < 2; mt++)
#pragma unroll
        for (int nt = 0; nt < 4; nt++) acc2[mt][nt] = z4;

    for (int k0 = 0; k0 < 192; k0 += 32) {
        int wr = tid & 127, wc = (tid >> 7) * 16;
        bf16x8 w0 = *(const bf16x8*)(eu1W + (size_t)wr * 192 + k0 + wc);
        bf16x8 w1 = *(const bf16x8*)(eu1W + (size_t)wr * 192 + k0 + wc + 8);
        __syncthreads();   // med writes visible; previous Ws reads done
        *(bf16x8*)&Ws[wr][wc]     = w0;
        *(bf16x8*)&Ws[wr][wc + 8] = w1;
        __syncthreads();
        bf16x8 af[2], bv[4];
#pragma unroll
        for (int mt = 0; mt < 2; mt++) af[mt] = *(const bf16x8*)&med[wm1 + mt * 16 + fr][k0 + fk];
#pragma unroll
        for (int nt = 0; nt < 4; nt++) bv[nt] = *(const bf16x8*)&Ws[wn1 + nt * 16 + fr][fk];
#pragma unroll
        for (int mt = 0; mt < 2; mt++)
#pragma unroll
            for (int nt = 0; nt < 4; nt++)
                acc2[mt][nt] = __builtin_amdgcn_mfma_f32_16x16x32_bf16(af[mt], bv[nt], acc2[mt][nt], 0, 0, 0);
    }
#pragma unroll
    for (int mt = 0; mt < 2; mt++)
#pragma unroll
        for (int nt = 0; nt < 4; nt++)
#pragma unroll
            for (int i = 0; i < 4; i++) {
                int row = wm1 + mt * 16 + cr + i;
                int col = wn1 + nt * 16 + cc;
                t2s[row][col] = (bf16)fmaxf(acc2[mt][nt][i] + eu1b[col], 0.f);
            }

    // ---------- stage 3: ea' (out 64x64, K=128; wave = 32x32) ----------
    const int wm3 = (wave & 1) * 32, wn3 = (wave >> 1) * 32;
    floatx4 acc3[2][2];
#pragma unroll
    for (int mt = 0; mt < 2; mt++)
#pragma unroll
        for (int nt = 0; nt < 2; nt++) acc3[mt][nt] = z4;

    for (int k0 = 0; k0 < 128; k0 += 32) {
        int wr = tid & 63, wc = (tid >> 6) * 8;
        bf16x8 w0 = *(const bf16x8*)(eu2W + (size_t)wr * 128 + k0 + wc);
        __syncthreads();   // t2s writes visible; previous Ws reads done
        *(bf16x8*)&Ws[wr][wc] = w0;
        __syncthreads();
        bf16x8 af[2], bv[2];
#pragma unroll
        for (int mt = 0; mt < 2; mt++) af[mt] = *(const bf16x8*)&t2s[wm3 + mt * 16 + fr][k0 + fk];
#pragma unroll
        for (int nt = 0; nt < 2; nt++) bv[nt] = *(const bf16x8*)&Ws[wn3 + nt * 16 + fr][fk];
#pragma unroll
        for (int mt = 0; mt < 2; mt++)
#pragma unroll
            for (int nt = 0; nt < 2; nt++)
                acc3[mt][nt] = __builtin_amdgcn_mfma_f32_16x16x32_bf16(af[mt], bv[nt], acc3[mt][nt], 0, 0, 0);
    }
#pragma unroll
    for (int mt = 0; mt < 2; mt++)
#pragma unroll
        for (int nt = 0; nt < 2; nt++)
#pragma unroll
            for (int i = 0; i < 4; i++) {
                int row = wm3 + mt * 16 + cr + i;
                int col = wn3 + nt * 16 + cc;
                float v = acc3[mt][nt][i] + eu2b[col];
                size_t o = (size_t)(e0 + row) * 64 + col;
                ea_out_f[o] = v;
                ea_out_b[o] = (bf16)v;
            }
}

// ---------------------------------------------------------------------------
// Post-MLP as per-tower MFMA GEMM (validated green in R8).
// ---------------------------------------------------------------------------
__global__ __launch_bounds__(256) void k_postg(
    const float* __restrict__ xin, const float* __restrict__ aggX,
    const float* __restrict__ aggS, const float* __restrict__ aggM,
    const bf16* __restrict__ qWbf, const float* __restrict__ qb,
    bf16* __restrict__ ybf)
{
    __shared__ bf16 As[64][40];
    __shared__ bf16 Ws[32][40];
    const int n0 = blockIdx.x * 64, t = blockIdx.y;
    const int tid = threadIdx.x, wave = tid >> 6, lane = tid & 63;
    const int lrow = tid >> 2, lcol = (tid & 3) * 8;
    const int fr = lane & 15, fk = (lane >> 4) * 8;
    floatx4 acc0 = {0,0,0,0}, acc1 = {0,0,0,0};

    for (int k0 = 0; k0 < 512; k0 += 32) {
        int n = n0 + lrow;
        int c0 = k0 + lcol;
        const float* srcp;
        if (c0 < 128)      srcp = xin  + (size_t)n * 128 + c0;
        else if (c0 < 256) srcp = aggX + (size_t)n * 512 + t * 128 + (c0 - 128);
        else if (c0 < 384) srcp = aggS + (size_t)n * 512 + t * 128 + (c0 - 256);
        else               srcp = aggM + (size_t)n * 512 + t * 128 + (c0 - 384);
        bf16 a8[8];
#pragma unroll
        for (int j = 0; j < 8; j++) a8[j] = (bf16)srcp[j];
        bf16 w8[8];
        if (tid < 128) {
            int wr = tid >> 2, wc = (tid & 3) * 8;
            *(bf16x8*)w8 = *(const bf16x8*)(qWbf + (size_t)(t * 32 + wr) * 512 + k0 + wc);
        }
        __syncthreads();
        *(bf16x8*)&As[lrow][lcol] = *(bf16x8*)a8;
        if (tid < 128) {
            int wr = tid >> 2, wc = (tid & 3) * 8;
            *(bf16x8*)&Ws[wr][wc] = *(bf16x8*)w8;
        }
        __syncthreads();
        bf16x8 a  = *(const bf16x8*)&As[wave * 16 + fr][fk];
        bf16x8 b0 = *(const bf16x8*)&Ws[fr][fk];
        bf16x8 b1 = *(const bf16x8*)&Ws[16 + fr][fk];
        acc0 = __builtin_amdgcn_mfma_f32_16x16x32_bf16(a, b0, acc0, 0, 0, 0);
        acc1 = __builtin_amdgcn_mfma_f32_16x16x32_bf16(a, b1, acc1, 0, 0, 0);
    }
    const int cc = lane & 15, cr = (lane >> 4) * 4;
#pragma unroll
    for (int i = 0; i < 4; i++) {
        int gn = n0 + wave * 16 + cr + i;
        ybf[(size_t)gn * 128 + t * 32 + cc]      = (bf16)(acc0[i] + qb[t * 32 + cc]);
        ybf[(size_t)gn * 128 + t * 32 + 16 + cc] = (bf16)(acc1[i] + qb[t * 32 + 16 + cc]);
    }
}

// ---------------------------------------------------------------------------
// Fold edge-encoder into pre-MLP (validated green in R8).
// ---------------------------------------------------------------------------
__global__ __launch_bounds__(64) void k_wcomb(
    const float* __restrict__ preW, const float* __restrict__ encW,
    const float* __restrict__ encb, const float* __restrict__ preb,
    bf16* __restrict__ wcomb, float* __restrict__ bcomb)
{
    int tf = blockIdx.x, d = threadIdx.x;
    __shared__ float pw[128];
    __shared__ float red[64];
    const float* pr = preW + (size_t)tf * 384 + 256;
    pw[d]      = pr[d];
    pw[d + 64] = pr[d + 64];
    __syncthreads();
    float acc = 0.f;
    for (int h = 0; h < 128; h++) acc += pw[h] * encW[h * 64 + d];
    wcomb[tf * 64 + d] = (bf16)acc;
    float b = pw[d] * encb[d] + pw[d + 64] * encb[d + 64];
    red[d] = b;
    __syncthreads();
    for (int s = 32; s > 0; s >>= 1) { if (d < s) red[d] += red[d + s]; __syncthreads(); }
    if (d == 0) bcomb[tf] = red[0] + preb[tf];
}

// ----------------------- CSR build -----------------------------------------
__global__ void k_count(const int* __restrict__ dst, int* __restrict__ counts)
{
    int e = blockIdx.x * 256 + threadIdx.x;
    atomicAdd(&counts[dst[e]], 1);
}

__global__ __launch_bounds__(1024) void k_scan(
    const int* __restrict__ counts, int* __restrict__ offs, int* __restrict__ cursor)
{
    __shared__ int ls[1024];
    int tid = threadIdx.x, base = tid * 4;
    int c0 = counts[base], c1 = counts[base + 1], c2 = counts[base + 2], c3 = counts[base + 3];
    ls[tid] = c0 + c1 + c2 + c3;
    __syncthreads();
    for (int d = 1; d < 1024; d <<= 1) {
        int v = (tid >= d) ? ls[tid - d] : 0;
        __syncthreads();
        ls[tid] += v;
        __syncthreads();
    }
    int r = tid ? ls[tid - 1] : 0;
    offs[base] = r;     cursor[base] = r;     r += c0;
    offs[base + 1] = r; cursor[base + 1] = r; r += c1;
    offs[base + 2] = r; cursor[base + 2] = r; r += c2;
    offs[base + 3] = r; cursor[base + 3] = r; r += c3;
    if (tid == 1023) offs[4096] = r;
}

__global__ void k_fill(const int* __restrict__ dst, int* __restrict__ cursor,
                       int* __restrict__ eord)
{
    int e = blockIdx.x * 256 + threadIdx.x;
    int p = atomicAdd(&cursor[dst[e]], 1);
    eord[p] = e;
}

// ---------------------------------------------------------------------------
// Aggregation over a 256-col half: msg = Pd[n] + Ps[src] + Q[e]  (bcomb folded
// into Pd via GEMM bias). grid=N, block=128, 2 cols/thread.
// ---------------------------------------------------------------------------
__global__ __launch_bounds__(128) void k_agg(
    const float* __restrict__ Pd, const float* __restrict__ Ps,
    const bf16* __restrict__ Qh,
    const int* __restrict__ src, const int* __restrict__ offs,
    const int* __restrict__ eord,
    float* __restrict__ aggX, float* __restrict__ aggS, float* __restrict__ aggM,
    int half)
{
    int n = blockIdx.x, tid = threadIdx.x;
    int c = half * 256 + tid * 2;
    float2 pd = *(const float2*)(Pd + (size_t)n * 512 + c);
    float p0 = pd.x, p1 = pd.y;
    float s0 = 0.f, s1 = 0.f, q0 = 0.f, q1 = 0.f;
    float x0 = -3e38f, x1 = -3e38f;
    int beg = offs[n], end = offs[n + 1];
    for (int i = beg; i < end; i++) {
        int e = eord[i];
        int sn = src[e];
        float2 ps = *(const float2*)(Ps + (size_t)sn * 512 + c);
        bf16x2 qv = *(const bf16x2*)(Qh + (size_t)e * 256 + tid * 2);
        float m0 = p0 + ps.x + (float)qv[0];
        float m1 = p1 + ps.y + (float)qv[1];
        s0 += m0; s1 += m1;
        q0 += m0 * m0; q1 += m1 * m1;
        x0 = fmaxf(x0, m0); x1 = fmaxf(x1, m1);
    }
    int cnt = end - beg;
    float inv = 1.f / fmaxf((float)cnt, 1.f);
    float me0 = s0 * inv, me1 = s1 * inv;
    float v0 = fmaxf(q0 * inv - me0 * me0, 0.f);
    float v1 = fmaxf(q1 * inv - me1 * me1, 0.f);
    size_t o = (size_t)n * 512 + c;
    aggX[o]     = cnt > 0 ? x0 : 0.f;
    aggX[o + 1] = cnt > 0 ? x1 : 0.f;
    aggS[o]     = sqrtf(v0 + 1e-5f);
    aggS[o + 1] = sqrtf(v1 + 1e-5f);
    aggM[o]     = me0;
    aggM[o + 1] = me1;
}

// --------------------------- GRU elementwise --------------------------------
__global__ void k_gru(const float* __restrict__ gi, const float* __restrict__ gh,
                      float* __restrict__ hst, bf16* __restrict__ ob)
{
    int i = blockIdx.x * 256 + threadIdx.x;
    int k = i & 127;
    size_t b = (size_t)(i >> 7) * 384;
    float ir = gi[b + k],       hr = gh[b + k];
    float iz = gi[b + 128 + k], hz = gh[b + 128 + k];
    float ic = gi[b + 256 + k], hc = gh[b + 256 + k];
    float r = 1.f / (1.f + __expf(-(ir + hr)));
    float z = 1.f / (1.f + __expf(-(iz + hz)));
    float c = tanhf(ic + r * hc);
    float h = hst[i];
    float hn = (1.f - z) * c + z * h;
    hst[i] = hn;
    ob[i] = (bf16)hn;
}

__global__ void k_writeout(const float* __restrict__ of, const float* __restrict__ ea,
                           float* __restrict__ o)
{
    size_t i = (size_t)blockIdx.x * 256 + threadIdx.x;
    if (i < 524288)            o[i] = of[i];
    else if (i < 4718592)      o[i] = ea[i - 524288];
    else                       o[i] = of[i - 4718592];
}

__global__ void k_sentinel(float* __restrict__ o, float v)
{
    int i = blockIdx.x * 256 + threadIdx.x;
    o[i] = v;
}

// ===========================================================================
extern "C" void kernel_launch(void* const* d_in, const int* in_sizes, int n_in,
                              void* d_out, int out_size, void* d_ws, size_t ws_size,
                              hipStream_t stream)
{
    static const int exp_sizes[23] = {
        524288, 4194304, 131072, 24576, 384, 589824, 1536, 196608, 384,
        49152, 384, 49152, 49152, 384, 384, 65536, 256, 32768, 128,
        24576, 128, 8192, 64 };
    if (n_in != 23) { k_sentinel<<<2048, 256, 0, stream>>>((float*)d_out, 200.f); return; }
    for (int i = 0; i < 23; i++)
        if (in_sizes[i] != exp_sizes[i]) {
            k_sentinel<<<2048, 256, 0, stream>>>((float*)d_out, 60.f + 4.f * i);
            return;
        }
    if (out_size != 5242880) { k_sentinel<<<2048, 256, 0, stream>>>((float*)d_out, 52.f); return; }

    const int* eidx = (const int*)d_in[2];

    char* w = (char*)d_ws;
    size_t off = 0;
    auto alloc = [&](size_t bytes) -> char* {
        char* p = w + off;
        off = (off + bytes + 255) & ~(size_t)255;
        return p;
    };
    int*   dflag   = (int*)  alloc(256);
    int*   iflag   = (int*)  alloc(256);
    int*   srcW    = (int*)  alloc((size_t)EE * 4);
    int*   dstW    = (int*)  alloc((size_t)EE * 4);
    float* out_f32 = (float*)alloc((size_t)NN * HH * 4);
    bf16*  out_bf  = (bf16*) alloc((size_t)NN * HH * 2);
    bf16*  m_bf    = (bf16*) alloc((size_t)NN * HH * 2);
    bf16*  ybf     = (bf16*) alloc((size_t)NN * HH * 2);
    float* ea_f32  = (float*)alloc((size_t)EE * EDD * 4);
    bf16*  ea_bf   = (bf16*) alloc((size_t)EE * EDD * 2);
    bf16*  wcombBf = (bf16*) alloc((size_t)THD * EDD * 2);
    float* bcomb   = (float*)alloc((size_t)THD * 4);
    int*   counts  = (int*)  alloc((size_t)NN * 4);
    int*   offs    = (int*)  alloc((size_t)(NN + 1) * 4);
    int*   cursor  = (int*)  alloc((size_t)NN * 4);
    int*   eord    = (int*)  alloc((size_t)EE * 4);
    float* aggX    = (float*)alloc((size_t)NN * THD * 4);
    float* aggS    = (float*)alloc((size_t)NN * THD * 4);
    float* aggM    = (float*)alloc((size_t)NN * THD * 4);
    float* encWc  = (float*)alloc((size_t)24576 * 4);
    float* encbc  = (float*)alloc((size_t)384 * 4);
    float* preWc  = (float*)alloc((size_t)589824 * 4);
    float* prebc  = (float*)alloc((size_t)1536 * 4);
    float* postbc = (float*)alloc((size_t)384 * 4);
    float* linbc  = (float*)alloc((size_t)384 * 4);
    float* bihc   = (float*)alloc((size_t)384 * 4);
    float* bhhc   = (float*)alloc((size_t)384 * 4);
    float* em1bc  = (float*)alloc((size_t)256 * 4);
    float* em2bc  = (float*)alloc((size_t)128 * 4);
    float* eu1bc  = (float*)alloc((size_t)128 * 4);
    float* eu2bc  = (float*)alloc((size_t)64 * 4);
    bf16* preWbf = (bf16*)alloc((size_t)589824 * 2);
    bf16* postWbf= (bf16*)alloc((size_t)196608 * 2);
    bf16* linWbf = (bf16*)alloc((size_t)49152 * 2);
    bf16* WihBf  = (bf16*)alloc((size_t)49152 * 2);
    bf16* WhhBf  = (bf16*)alloc((size_t)49152 * 2);
    bf16* em1Wbf = (bf16*)alloc((size_t)65536 * 2);
    bf16* em2Wbf = (bf16*)alloc((size_t)32768 * 2);
    bf16* eu1Wbf = (bf16*)alloc((size_t)24576 * 2);
    bf16* eu2Wbf = (bf16*)alloc((size_t)8192 * 2);
    // phase-shared region (50.4 MB)
    char* region = alloc((size_t)50331648);
    // PNA phase: Pd/Ps f32 [N,512], Qh bf16 [E,256]
    float* Pd = (float*)(region);
    float* Ps = (float*)(region + 8388608);
    bf16*  Qh = (bf16*) (region + 16777216);    // 33.55 MB
    // GRU phase:
    float* gi = (float*)(region);
    float* gh = (float*)(region + 6291456);
    // edge phase:
    float* SA = (float*)(region);               // [N,256]
    float* SB = (float*)(region + 4194304);

    if (ws_size < off) { k_sentinel<<<2048, 256, 0, stream>>>((float*)d_out, 44.f); return; }

    // ---- canonicalize ----
    k_detidx<<<1, 64, 0, stream>>>(eidx, iflag);
    k_extidx<<<EE / 256, 256, 0, stream>>>(eidx, srcW, dstW, iflag);
    k_detect<<<1, 64, 0, stream>>>(d_in[1], dflag);
    auto CF = [&](int idx, float* dst, int n) {
        k_canon_f<<<(n + 255) / 256, 256, 0, stream>>>(d_in[idx], dst, n, dflag);
    };
    auto CB = [&](int idx, bf16* dst, int n) {
        k_canon_b<<<(n + 255) / 256, 256, 0, stream>>>(d_in[idx], dst, n, dflag);
    };
    k_canon_fb<<<(NN * HH + 255) / 256, 256, 0, stream>>>(d_in[0], out_f32, out_bf, NN * HH, dflag);
    k_canon_fb<<<(EE * EDD + 255) / 256, 256, 0, stream>>>(d_in[1], ea_f32, ea_bf, EE * EDD, dflag);
    k_canon_fb<<<(589824 + 255) / 256, 256, 0, stream>>>(d_in[5], preWc, preWbf, 589824, dflag);
    CF(3, encWc, 24576);   CF(4, encbc, 384);   CF(6, prebc, 1536);
    CF(8, postbc, 384);    CF(10, linbc, 384);  CF(13, bihc, 384);  CF(14, bhhc, 384);
    CF(16, em1bc, 256);    CF(18, em2bc, 128);  CF(20, eu1bc, 128); CF(22, eu2bc, 64);
    CB(7, postWbf, 196608); CB(9, linWbf, 49152);
    CB(11, WihBf, 49152);   CB(12, WhhBf, 49152);
    CB(15, em1Wbf, 65536);  CB(17, em2Wbf, 32768);
    CB(19, eu1Wbf, 24576);  CB(21, eu2Wbf, 8192);

    auto GEMM = [&](const bf16* A, int lda, const bf16* Wm, int ldw, const float* bias,
                    void* C, int ldc, int M, int Nout, int K, bool relu, int om) {
        dim3 grid(M / 64, Nout / 64);
        if (relu) {
            if (om) k_mgemm<true, 1><<<grid, 256, 0, stream>>>(A, lda, Wm, ldw, bias, C, ldc, K);
            else    k_mgemm<true, 0><<<grid, 256, 0, stream>>>(A, lda, Wm, ldw, bias, C, ldc, K);
        } else {
            if (om) k_mgemm<false, 1><<<grid, 256, 0, stream>>>(A, lda, Wm, ldw, bias, C, ldc, K);
            else    k_mgemm<false, 0><<<grid, 256, 0, stream>>>(A, lda, Wm, ldw, bias, C, ldc, K);
        }
    };

    // ---- CSR ----
    hipMemsetAsync(counts, 0, NN * 4, stream);
    k_count<<<EE / 256, 256, 0, stream>>>(dstW, counts);
    k_scan<<<1, 1024, 0, stream>>>(counts, offs, cursor);
    k_fill<<<EE / 256, 256, 0, stream>>>(dstW, cursor, eord);

    for (int l = 0; l < 3; l++) {
        const float* preW_l  = preWc  + (size_t)l * 196608;
        const bf16*  preWbf_l= preWbf + (size_t)l * 196608;
        const float* encW_l  = encWc  + (size_t)l * 8192;
        const float* encb_l  = encbc  + (size_t)l * 128;
        const float* preb_l  = prebc  + (size_t)l * 512;
        const bf16*  postW_l = postWbf + (size_t)l * 65536;
        const float* postb_l = postbc + (size_t)l * 128;
        const bf16*  linW_l  = linWbf + (size_t)l * 16384;
        const float* linb_l  = linbc  + (size_t)l * 128;

        // ---- PNA (factored; Pd carries bcomb via GEMM bias) ----
        k_wcomb<<<THD, 64, 0, stream>>>(preW_l, encW_l, encb_l, preb_l, wcombBf, bcomb);
        GEMM(out_bf, HH, preWbf_l,       384, bcomb,   Pd, 512, NN, 512, HH, false, 0);
        GEMM(out_bf, HH, preWbf_l + 128, 384, nullptr, Ps, 512, NN, 512, HH, false, 0);
        for (int half = 0; half < 2; half++) {
            GEMM(ea_bf, EDD, wcombBf + (size_t)half * 256 * 64, EDD, nullptr,
                 Qh, 256, EE, 256, EDD, false, 1);
            k_agg<<<NN, 128, 0, stream>>>(Pd, Ps, Qh, srcW, offs, eord,
                                          aggX, aggS, aggM, half);
        }
        k_postg<<<dim3(NN / 64, 4), 256, 0, stream>>>(out_f32, aggX, aggS, aggM,
                                                      postW_l, postb_l, ybf);
        GEMM(ybf, HH, linW_l, HH, linb_l, m_bf, HH, NN, HH, HH, true, 1);
        // ---- GRU ----
        GEMM(m_bf,   HH, WihBf, HH, bihc, gi, 384, NN, 384, HH, false, 0);
        GEMM(out_bf, HH, WhhBf, HH, bhhc, gh, 384, NN, 384, HH, false, 0);
        k_gru<<<NN * HH / 256, 256, 0, stream>>>(gi, gh, out_f32, out_bf);
        // ---- edge update (fused; em1b folded into SA bias) ----
        GEMM(out_bf, HH, em1Wbf,       256, em1bc,   SA, 256, NN, 256, HH, false, 0);
        GEMM(out_bf, HH, em1Wbf + 128, 256, nullptr, SB, 256, NN, 256, HH, false, 0);
        k_edge<<<EE / 64, 256, 0, stream>>>(SA, SB, em2Wbf, em2bc, eu1Wbf, eu1bc,
                                            eu2Wbf, eu2bc, srcW, dstW,
                                            ea_bf, ea_f32, ea_bf);
    }

    k_writeout<<<(2 * NN * HH + EE * EDD) / 256, 256, 0, stream>>>(out_f32, ea_f32, (float*)d_out);
}

// Round 10
// 590.287 us; speedup vs baseline: 5.2571x; 1.1165x over previous
//
#include <hip/hip_runtime.h>
#include <hip/hip_bf16.h>
#include <math.h>

#define NN 4096
#define EE 65536
#define HH 128
#define EDD 64
#define THD 512

typedef __bf16 bf16;
typedef __bf16 bf16x8 __attribute__((ext_vector_type(8)));
typedef __bf16 bf16x4 __attribute__((ext_vector_type(4)));
typedef float  floatx4 __attribute__((ext_vector_type(4)));

// ---------------------------------------------------------------------------
// input dtype detects (proven: floats f32, edge_index int32; cheap insurance)
// ---------------------------------------------------------------------------
__global__ __launch_bounds__(64) void k_detect(const void* __restrict__ p,
                                               int* __restrict__ flag)
{
    const bf16* b = (const bf16*)p;
    int t = threadIdx.x;
    int bad = 0;
    for (int i = 0; i < 32; i++) {
        float v = (float)b[t * 32 + i];
        if (!(v == v) || fabsf(v) > 100.f) bad = 1;
    }
    unsigned long long m = __ballot(bad);
    if (t == 0) *flag = (m == 0ULL) ? 1 : 0;
}

__global__ void k_canon_f(const void* __restrict__ src, float* __restrict__ dst,
                          int n, const int* __restrict__ flag)
{
    int i = blockIdx.x * 256 + threadIdx.x;
    if (i >= n) return;
    dst[i] = (*flag) ? (float)((const bf16*)src)[i] : ((const float*)src)[i];
}

__global__ void k_canon_b(const void* __restrict__ src, bf16* __restrict__ dst,
                          int n, const int* __restrict__ flag)
{
    int i = blockIdx.x * 256 + threadIdx.x;
    if (i >= n) return;
    dst[i] = (*flag) ? ((const bf16*)src)[i] : (bf16)((const float*)src)[i];
}

__global__ void k_canon_fb(const void* __restrict__ src, float* __restrict__ dst,
                           bf16* __restrict__ dst2, int n, const int* __restrict__ flag)
{
    int i = blockIdx.x * 256 + threadIdx.x;
    if (i >= n) return;
    float v = (*flag) ? (float)((const bf16*)src)[i] : ((const float*)src)[i];
    dst[i] = v;
    dst2[i] = (bf16)v;
}

// ea canon: natural-order f32 + CSR-ordered bf16 (scatter via pos)
__global__ void k_canon_ea(const void* __restrict__ src, float* __restrict__ dstf,
                           bf16* __restrict__ eaord, const int* __restrict__ pos,
                           const int* __restrict__ flag)
{
    int i = blockIdx.x * 256 + threadIdx.x;   // E*64
    int e = i >> 6, d = i & 63;
    float v = (*flag) ? (float)((const bf16*)src)[i] : ((const float*)src)[i];
    dstf[i] = v;
    eaord[(size_t)pos[e] * 64 + d] = (bf16)v;
}

__global__ __launch_bounds__(64) void k_detidx(const int* __restrict__ p,
                                               int* __restrict__ iflag)
{
    int t = threadIdx.x;
    int bad = 0;
    for (int i = 0; i < 8; i++) {
        int k = t * 8 + i;
        int lo = p[2 * k], hi = p[2 * k + 1];
        if (hi != 0 || lo < 0 || lo >= NN) bad = 1;
    }
    unsigned long long m = __ballot(bad);
    if (t == 0) *iflag = (m == 0ULL) ? 1 : 0;
}

__global__ void k_extidx(const int* __restrict__ p, int* __restrict__ srcW,
                         int* __restrict__ dstW, const int* __restrict__ iflag)
{
    int e = blockIdx.x * 256 + threadIdx.x;
    int s, d;
    if (*iflag) { s = p[2 * e];  d = p[2 * EE + 2 * e]; }
    else        { s = p[e];      d = p[EE + e]; }
    srcW[e] = min(max(s, 0), NN - 1);
    dstW[e] = min(max(d, 0), NN - 1);
}

// ---------------------------------------------------------------------------
// MFMA bf16 GEMM (validated): C[M,Nout] = act(A @ W^T + bias)
// ---------------------------------------------------------------------------
template<bool RELU, int OM>
__global__ __launch_bounds__(256) void k_mgemm(
    const bf16* __restrict__ A, int lda,
    const bf16* __restrict__ W, int ldw, const float* __restrict__ bias,
    void* __restrict__ Cv, int ldc, int K)
{
    __shared__ bf16 As[64][40];
    __shared__ bf16 Ws[64][40];
    const int m0 = blockIdx.x * 64, n0 = blockIdx.y * 64;
    const int tid = threadIdx.x, wave = tid >> 6, lane = tid & 63;
    const int wm = (wave & 1) * 32, wn = (wave >> 1) * 32;
    const int lrow = tid >> 2, lcol = (tid & 3) * 8;
    const int fr = lane & 15, fk = (lane >> 4) * 8;
    floatx4 acc00 = {0,0,0,0}, acc01 = {0,0,0,0}, acc10 = {0,0,0,0}, acc11 = {0,0,0,0};

    for (int k0 = 0; k0 < K; k0 += 32) {
        bf16x8 av = *(const bf16x8*)(A + (size_t)(m0 + lrow) * lda + k0 + lcol);
        bf16x8 wv = *(const bf16x8*)(W + (size_t)(n0 + lrow) * ldw + k0 + lcol);
        __syncthreads();
        *(bf16x8*)&As[lrow][lcol] = av;
        *(bf16x8*)&Ws[lrow][lcol] = wv;
        __syncthreads();
        bf16x8 a0 = *(const bf16x8*)&As[wm + fr][fk];
        bf16x8 a1 = *(const bf16x8*)&As[wm + 16 + fr][fk];
        bf16x8 b0 = *(const bf16x8*)&Ws[wn + fr][fk];
        bf16x8 b1 = *(const bf16x8*)&Ws[wn + 16 + fr][fk];
        acc00 = __builtin_amdgcn_mfma_f32_16x16x32_bf16(a0, b0, acc00, 0, 0, 0);
        acc01 = __builtin_amdgcn_mfma_f32_16x16x32_bf16(a0, b1, acc01, 0, 0, 0);
        acc10 = __builtin_amdgcn_mfma_f32_16x16x32_bf16(a1, b0, acc10, 0, 0, 0);
        acc11 = __builtin_amdgcn_mfma_f32_16x16x32_bf16(a1, b1, acc11, 0, 0, 0);
    }
    const int cc = lane & 15, cr = (lane >> 4) * 4;
    float vb0 = bias ? bias[n0 + wn + cc] : 0.f;
    float vb1 = bias ? bias[n0 + wn + 16 + cc] : 0.f;
    floatx4 accs[2][2] = {{acc00, acc01}, {acc10, acc11}};
#pragma unroll
    for (int mt = 0; mt < 2; mt++)
#pragma unroll
        for (int nt = 0; nt < 2; nt++) {
            float vb = nt ? vb1 : vb0;
#pragma unroll
            for (int i = 0; i < 4; i++) {
                int gm = m0 + wm + mt * 16 + cr + i;
                int gn = n0 + wn + nt * 16 + cc;
                float v = accs[mt][nt][i] + vb;
                if (RELU) v = fmaxf(v, 0.f);
                if (OM == 1) ((bf16*)Cv)[(size_t)gm * ldc + gn] = (bf16)v;
                else         ((float*)Cv)[(size_t)gm * ldc + gn] = v;
            }
        }
}

// ---------------------------------------------------------------------------
// Q GEMM, wide tile: Q_ord[E,512] = eaord[E,64] @ wcomb[512,64]^T
// grid=(E/64, 2), block=256. Block computes 64 rows x 256 cols, K=64 staged
// once. Wave w = cols w*64..w*64+63 (4x4 16x16 tiles).
// ---------------------------------------------------------------------------
__global__ __launch_bounds__(256) void k_qgemm(
    const bf16* __restrict__ eaord, const bf16* __restrict__ wcomb,
    bf16* __restrict__ Qord)
{
    __shared__ bf16 As[64][72];
    __shared__ bf16 Ws[256][72];
    const int e0 = blockIdx.x * 64, n0g = blockIdx.y * 256;
    const int tid = threadIdx.x, wave = tid >> 6, lane = tid & 63;
    const int fr = lane & 15, fk = (lane >> 4) * 8;
    const int cc = lane & 15, cr = (lane >> 4) * 4;

    // stage A: 64x64 (2 sweeps of 2048 elems)
#pragma unroll
    for (int v = 0; v < 2; v++) {
        int lin = v * 2048 + tid * 8;
        int r = lin >> 6, c = lin & 63;
        *(bf16x8*)&As[r][c] = *(const bf16x8*)(eaord + (size_t)(e0 + r) * 64 + c);
    }
    // stage W: 256x64 (8 sweeps)
#pragma unroll
    for (int v = 0; v < 8; v++) {
        int lin = v * 2048 + tid * 8;
        int r = lin >> 6, c = lin & 63;
        *(bf16x8*)&Ws[r][c] = *(const bf16x8*)(wcomb + (size_t)(n0g + r) * 64 + c);
    }
    __syncthreads();

    floatx4 acc[4][4];
#pragma unroll
    for (int mt = 0; mt < 4; mt++)
#pragma unroll
        for (int nt = 0; nt < 4; nt++) acc[mt][nt] = (floatx4){0,0,0,0};

#pragma unroll
    for (int kk = 0; kk < 64; kk += 32) {
        bf16x8 af[4], bv[4];
#pragma unroll
        for (int mt = 0; mt < 4; mt++) af[mt] = *(const bf16x8*)&As[mt * 16 + fr][kk + fk];
#pragma unroll
        for (int nt = 0; nt < 4; nt++) bv[nt] = *(const bf16x8*)&Ws[wave * 64 + nt * 16 + fr][kk + fk];
#pragma unroll
        for (int mt = 0; mt < 4; mt++)
#pragma unroll
            for (int nt = 0; nt < 4; nt++)
                acc[mt][nt] = __builtin_amdgcn_mfma_f32_16x16x32_bf16(af[mt], bv[nt], acc[mt][nt], 0, 0, 0);
    }
#pragma unroll
    for (int mt = 0; mt < 4; mt++)
#pragma unroll
        for (int nt = 0; nt < 4; nt++)
#pragma unroll
            for (int i = 0; i < 4; i++) {
                int row = mt * 16 + cr + i;
                int col = n0g + wave * 64 + nt * 16 + cc;
                Qord[(size_t)(e0 + row) * 512 + col] = (bf16)acc[mt][nt][i];
            }
}

// ---------------------------------------------------------------------------
// Fused edge update (SAB merged, ea in CSR order via pos). Validated green
// structure from R9; only addressing changed.
// ---------------------------------------------------------------------------
__global__ __launch_bounds__(256) void k_edge(
    const float* __restrict__ SAB,
    const bf16* __restrict__ em2W, const float* __restrict__ em2b,
    const bf16* __restrict__ eu1W, const float* __restrict__ eu1b,
    const bf16* __restrict__ eu2W, const float* __restrict__ eu2b,
    const int* __restrict__ src, const int* __restrict__ dst,
    const int* __restrict__ pos,
    bf16* __restrict__ eaord, float* __restrict__ ea_out_f)
{
    __shared__ bf16 Ws[128][40];
    __shared__ bf16 As[64][40];
    __shared__ bf16 med[64][200];   // cols 0..127 m_ed, 128..191 ea
    __shared__ bf16 t2s[64][136];
    const int e0 = blockIdx.x * 64;
    const int tid = threadIdx.x, wave = tid >> 6, lane = tid & 63;
    const int lrow = tid >> 2, lcol = (tid & 3) * 8;
    const int fr = lane & 15, fk = (lane >> 4) * 8;
    const int cc = lane & 15, cr = (lane >> 4) * 4;
    const int sI = src[e0 + lrow], dI = dst[e0 + lrow];
    const floatx4 z4 = {0.f, 0.f, 0.f, 0.f};

    // ---------- stage 1: m_ed ----------
    const int wm1 = (wave & 1) * 32, wn1 = (wave >> 1) * 64;
    floatx4 acc1[2][4];
#pragma unroll
    for (int mt = 0; mt < 2; mt++)
#pragma unroll
        for (int nt = 0; nt < 4; nt++) acc1[mt][nt] = z4;

    for (int k0 = 0; k0 < 256; k0 += 32) {
        bf16 a8[8];
#pragma unroll
        for (int j = 0; j < 8; j++) {
            int c = k0 + lcol + j;
            a8[j] = (bf16)fmaxf(SAB[(size_t)sI * 512 + c] + SAB[(size_t)dI * 512 + 256 + c], 0.f);
        }
        int wr = tid & 127, wc = (tid >> 7) * 16;
        bf16x8 w0 = *(const bf16x8*)(em2W + (size_t)wr * 256 + k0 + wc);
        bf16x8 w1 = *(const bf16x8*)(em2W + (size_t)wr * 256 + k0 + wc + 8);
        __syncthreads();
        *(bf16x8*)&As[lrow][lcol] = *(bf16x8*)a8;
        *(bf16x8*)&Ws[wr][wc]     = w0;
        *(bf16x8*)&Ws[wr][wc + 8] = w1;
        __syncthreads();
        bf16x8 af[2], bv[4];
#pragma unroll
        for (int mt = 0; mt < 2; mt++) af[mt] = *(const bf16x8*)&As[wm1 + mt * 16 + fr][fk];
#pragma unroll
        for (int nt = 0; nt < 4; nt++) bv[nt] = *(const bf16x8*)&Ws[wn1 + nt * 16 + fr][fk];
#pragma unroll
        for (int mt = 0; mt < 2; mt++)
#pragma unroll
            for (int nt = 0; nt < 4; nt++)
                acc1[mt][nt] = __builtin_amdgcn_mfma_f32_16x16x32_bf16(af[mt], bv[nt], acc1[mt][nt], 0, 0, 0);
    }
#pragma unroll
    for (int mt = 0; mt < 2; mt++)
#pragma unroll
        for (int nt = 0; nt < 4; nt++)
#pragma unroll
            for (int i = 0; i < 4; i++) {
                int row = wm1 + mt * 16 + cr + i;
                int col = wn1 + nt * 16 + cc;
                med[row][col] = (bf16)fmaxf(acc1[mt][nt][i] + em2b[col], 0.f);
            }
    // append ea tile (CSR-ordered rows via pos)
    {
        int r = tid >> 2, c0 = (tid & 3) * 16;
        int pr = pos[e0 + r];
        bf16x8 v0 = *(const bf16x8*)(eaord + (size_t)pr * 64 + c0);
        bf16x8 v1 = *(const bf16x8*)(eaord + (size_t)pr * 64 + c0 + 8);
        *(bf16x8*)&med[r][128 + c0]     = v0;
        *(bf16x8*)&med[r][128 + c0 + 8] = v1;
    }

    // ---------- stage 2: t2 ----------
    floatx4 acc2[2][4];
#pragma unroll
    for (int mt = 0; mt < 2; mt++)
#pragma unroll
        for (int nt = 0; nt < 4; nt++) acc2[mt][nt] = z4;

    for (int k0 = 0; k0 < 192; k0 += 32) {
        int wr = tid & 127, wc = (tid >> 7) * 16;
        bf16x8 w0 = *(const bf16x8*)(eu1W + (size_t)wr * 192 + k0 + wc);
        bf16x8 w1 = *(const bf16x8*)(eu1W + (size_t)wr * 192 + k0 + wc + 8);
        __syncthreads();
        *(bf16x8*)&Ws[wr][wc]     = w0;
        *(bf16x8*)&Ws[wr][wc + 8] = w1;
        __syncthreads();
        bf16x8 af[2], bv[4];
#pragma unroll
        for (int mt = 0; mt < 2; mt++) af[mt] = *(const bf16x8*)&med[wm1 + mt * 16 + fr][k0 + fk];
#pragma unroll
        for (int nt = 0; nt < 4; nt++) bv[nt] = *(const bf16x8*)&Ws[wn1 + nt * 16 + fr][fk];
#pragma unroll
        for (int mt = 0; mt < 2; mt++)
#pragma unroll
            for (int nt = 0; nt < 4; nt++)
                acc2[mt][nt] = __builtin_amdgcn_mfma_f32_16x16x32_bf16(af[mt], bv[nt], acc2[mt][nt], 0, 0, 0);
    }
#pragma unroll
    for (int mt = 0; mt < 2; mt++)
#pragma unroll
        for (int nt = 0; nt < 4; nt++)
#pragma unroll
            for (int i = 0; i < 4; i++) {
                int row = wm1 + mt * 16 + cr + i;
                int col = wn1 + nt * 16 + cc;
                t2s[row][col] = (bf16)fmaxf(acc2[mt][nt][i] + eu1b[col], 0.f);
            }

    // ---------- stage 3: ea' ----------
    const int wm3 = (wave & 1) * 32, wn3 = (wave >> 1) * 32;
    floatx4 acc3[2][2];
#pragma unroll
    for (int mt = 0; mt < 2; mt++)
#pragma unroll
        for (int nt = 0; nt < 2; nt++) acc3[mt][nt] = z4;

    for (int k0 = 0; k0 < 128; k0 += 32) {
        int wr = tid & 63, wc = (tid >> 6) * 8;
        bf16x8 w0 = *(const bf16x8*)(eu2W + (size_t)wr * 128 + k0 + wc);
        __syncthreads();
        *(bf16x8*)&Ws[wr][wc] = w0;
        __syncthreads();
        bf16x8 af[2], bv[2];
#pragma unroll
        for (int mt = 0; mt < 2; mt++) af[mt] = *(const bf16x8*)&t2s[wm3 + mt * 16 + fr][k0 + fk];
#pragma unroll
        for (int nt = 0; nt < 2; nt++) bv[nt] = *(const bf16x8*)&Ws[wn3 + nt * 16 + fr][fk];
#pragma unroll
        for (int mt = 0; mt < 2; mt++)
#pragma unroll
            for (int nt = 0; nt < 2; nt++)
                acc3[mt][nt] = __builtin_amdgcn_mfma_f32_16x16x32_bf16(af[mt], bv[nt], acc3[mt][nt], 0, 0, 0);
    }
#pragma unroll
    for (int mt = 0; mt < 2; mt++)
#pragma unroll
        for (int nt = 0; nt < 2; nt++)
#pragma unroll
            for (int i = 0; i < 4; i++) {
                int row = wm3 + mt * 16 + cr + i;
                int col = wn3 + nt * 16 + cc;
                float v = acc3[mt][nt][i] + eu2b[col];
                int e = e0 + row;
                ea_out_f[(size_t)e * 64 + col] = v;
                eaord[(size_t)pos[e] * 64 + col] = (bf16)v;
            }
}

// ---------------------------------------------------------------------------
// Post-MLP per-tower MFMA GEMM (validated green in R8/R9).
// ---------------------------------------------------------------------------
__global__ __launch_bounds__(256) void k_postg(
    const float* __restrict__ xin, const float* __restrict__ aggX,
    const float* __restrict__ aggS, const float* __restrict__ aggM,
    const bf16* __restrict__ qWbf, const float* __restrict__ qb,
    bf16* __restrict__ ybf)
{
    __shared__ bf16 As[64][40];
    __shared__ bf16 Ws[32][40];
    const int n0 = blockIdx.x * 64, t = blockIdx.y;
    const int tid = threadIdx.x, wave = tid >> 6, lane = tid & 63;
    const int lrow = tid >> 2, lcol = (tid & 3) * 8;
    const int fr = lane & 15, fk = (lane >> 4) * 8;
    floatx4 acc0 = {0,0,0,0}, acc1 = {0,0,0,0};

    for (int k0 = 0; k0 < 512; k0 += 32) {
        int n = n0 + lrow;
        int c0 = k0 + lcol;
        const float* srcp;
        if (c0 < 128)      srcp = xin  + (size_t)n * 128 + c0;
        else if (c0 < 256) srcp = aggX + (size_t)n * 512 + t * 128 + (c0 - 128);
        else if (c0 < 384) srcp = aggS + (size_t)n * 512 + t * 128 + (c0 - 256);
        else               srcp = aggM + (size_t)n * 512 + t * 128 + (c0 - 384);
        bf16 a8[8];
#pragma unroll
        for (int j = 0; j < 8; j++) a8[j] = (bf16)srcp[j];
        bf16 w8[8];
        if (tid < 128) {
            int wr = tid >> 2, wc = (tid & 3) * 8;
            *(bf16x8*)w8 = *(const bf16x8*)(qWbf + (size_t)(t * 32 + wr) * 512 + k0 + wc);
        }
        __syncthreads();
        *(bf16x8*)&As[lrow][lcol] = *(bf16x8*)a8;
        if (tid < 128) {
            int wr = tid >> 2, wc = (tid & 3) * 8;
            *(bf16x8*)&Ws[wr][wc] = *(bf16x8*)w8;
        }
        __syncthreads();
        bf16x8 a  = *(const bf16x8*)&As[wave * 16 + fr][fk];
        bf16x8 b0 = *(const bf16x8*)&Ws[fr][fk];
        bf16x8 b1 = *(const bf16x8*)&Ws[16 + fr][fk];
        acc0 = __builtin_amdgcn_mfma_f32_16x16x32_bf16(a, b0, acc0, 0, 0, 0);
        acc1 = __builtin_amdgcn_mfma_f32_16x16x32_bf16(a, b1, acc1, 0, 0, 0);
    }
    const int cc = lane & 15, cr = (lane >> 4) * 4;
#pragma unroll
    for (int i = 0; i < 4; i++) {
        int gn = n0 + wave * 16 + cr + i;
        ybf[(size_t)gn * 128 + t * 32 + cc]      = (bf16)(acc0[i] + qb[t * 32 + cc]);
        ybf[(size_t)gn * 128 + t * 32 + 16 + cc] = (bf16)(acc1[i] + qb[t * 32 + 16 + cc]);
    }
}

// ---------------------------------------------------------------------------
// Fold edge-encoder into pre-MLP; writes zero-extended bias [1024].
// ---------------------------------------------------------------------------
__global__ __launch_bounds__(64) void k_wcomb(
    const float* __restrict__ preW, const float* __restrict__ encW,
    const float* __restrict__ encb, const float* __restrict__ preb,
    bf16* __restrict__ wcomb, float* __restrict__ bcombext)
{
    int tf = blockIdx.x, d = threadIdx.x;
    __shared__ float pw[128];
    __shared__ float red[64];
    const float* pr = preW + (size_t)tf * 384 + 256;
    pw[d]      = pr[d];
    pw[d + 64] = pr[d + 64];
    __syncthreads();
    float acc = 0.f;
    for (int h = 0; h < 128; h++) acc += pw[h] * encW[h * 64 + d];
    wcomb[tf * 64 + d] = (bf16)acc;
    float b = pw[d] * encb[d] + pw[d + 64] * encb[d + 64];
    red[d] = b;
    __syncthreads();
    for (int s = 32; s > 0; s >>= 1) { if (d < s) red[d] += red[d + s]; __syncthreads(); }
    if (d == 0) {
        bcombext[tf] = red[0] + preb[tf];
        bcombext[512 + tf] = 0.f;
    }
}

// ---------------- weight repacks (once per launch) --------------------------
// Wnode[l][1024,128]: rows 0..511 = preW[tf][0:128] (x_dst), 512..1023 = preW[tf][128:256]
__global__ void k_rep_node(const bf16* __restrict__ preWbf, bf16* __restrict__ Wnode)
{
    int i = blockIdx.x * 256 + threadIdx.x;   // 3*1024*128
    int l = i >> 17, rem = i & 131071;
    int r = rem >> 7, c = rem & 127;
    bf16 v = (r < 512) ? preWbf[(size_t)l * 196608 + (size_t)r * 384 + c]
                       : preWbf[(size_t)l * 196608 + (size_t)(r - 512) * 384 + 128 + c];
    Wnode[i] = v;
}

// Wem1[512,128]: rows 0..255 = em1W[f][0:128], 256..511 = em1W[f][128:256]
__global__ void k_rep_em1(const bf16* __restrict__ em1Wbf, bf16* __restrict__ Wem1)
{
    int i = blockIdx.x * 256 + threadIdx.x;   // 512*128
    int r = i >> 7, c = i & 127;
    bf16 v = (r < 256) ? em1Wbf[(size_t)r * 256 + c]
                       : em1Wbf[(size_t)(r - 256) * 256 + 128 + c];
    Wem1[i] = v;
}

__global__ void k_ext_em1b(const float* __restrict__ em1b, float* __restrict__ ext)
{
    int i = blockIdx.x * 256 + threadIdx.x;   // 512
    ext[i] = (i < 256) ? em1b[i] : 0.f;
}

// ----------------------- CSR build -----------------------------------------
__global__ void k_count(const int* __restrict__ dst, int* __restrict__ counts)
{
    int e = blockIdx.x * 256 + threadIdx.x;
    atomicAdd(&counts[dst[e]], 1);
}

__global__ __launch_bounds__(1024) void k_scan(
    const int* __restrict__ counts, int* __restrict__ offs, int* __restrict__ cursor)
{
    __shared__ int ls[1024];
    int tid = threadIdx.x, base = tid * 4;
    int c0 = counts[base], c1 = counts[base + 1], c2 = counts[base + 2], c3 = counts[base + 3];
    ls[tid] = c0 + c1 + c2 + c3;
    __syncthreads();
    for (int d = 1; d < 1024; d <<= 1) {
        int v = (tid >= d) ? ls[tid - d] : 0;
        __syncthreads();
        ls[tid] += v;
        __syncthreads();
    }
    int r = tid ? ls[tid - 1] : 0;
    offs[base] = r;     cursor[base] = r;     r += c0;
    offs[base + 1] = r; cursor[base + 1] = r; r += c1;
    offs[base + 2] = r; cursor[base + 2] = r; r += c2;
    offs[base + 3] = r; cursor[base + 3] = r; r += c3;
    if (tid == 1023) offs[4096] = r;
}

// fill: also emits pos[e] (CSR position) and srcord (src gathered to CSR order)
__global__ void k_fill(const int* __restrict__ dst, const int* __restrict__ srcW,
                       int* __restrict__ cursor, int* __restrict__ pos,
                       int* __restrict__ srcord)
{
    int e = blockIdx.x * 256 + threadIdx.x;
    int p = atomicAdd(&cursor[dst[e]], 1);
    pos[e] = p;
    srcord[p] = srcW[e];
}

// ---------------------------------------------------------------------------
// Single-pass aggregation over all 512 cols. grid=N, block=128, 4 cols/thread.
// Pd = PdPs[n][c] (bcomb in bias), Ps = PdPs[src][512+c], Q coalesced (CSR order).
// ---------------------------------------------------------------------------
__global__ __launch_bounds__(128) void k_agg(
    const float* __restrict__ PdPs, const bf16* __restrict__ Qord,
    const int* __restrict__ srcord, const int* __restrict__ offs,
    float* __restrict__ aggX, float* __restrict__ aggS, float* __restrict__ aggM)
{
    int n = blockIdx.x, tid = threadIdx.x;
    int c = tid * 4;
    float4 pd = *(const float4*)(PdPs + (size_t)n * 1024 + c);
    float s0 = 0, s1 = 0, s2 = 0, s3 = 0;
    float q0 = 0, q1 = 0, q2 = 0, q3 = 0;
    float x0 = -3e38f, x1 = -3e38f, x2 = -3e38f, x3 = -3e38f;
    int beg = offs[n], end = offs[n + 1];
    for (int i = beg; i < end; i++) {
        int sn = srcord[i];
        float4 ps = *(const float4*)(PdPs + (size_t)sn * 1024 + 512 + c);
        bf16x4 qv = *(const bf16x4*)(Qord + (size_t)i * 512 + c);
        float m0 = pd.x + ps.x + (float)qv[0];
        float m1 = pd.y + ps.y + (float)qv[1];
        float m2 = pd.z + ps.z + (float)qv[2];
        float m3 = pd.w + ps.w + (float)qv[3];
        s0 += m0; s1 += m1; s2 += m2; s3 += m3;
        q0 += m0 * m0; q1 += m1 * m1; q2 += m2 * m2; q3 += m3 * m3;
        x0 = fmaxf(x0, m0); x1 = fmaxf(x1, m1); x2 = fmaxf(x2, m2); x3 = fmaxf(x3, m3);
    }
    int cnt = end - beg;
    float inv = 1.f / fmaxf((float)cnt, 1.f);
    float me0 = s0 * inv, me1 = s1 * inv, me2 = s2 * inv, me3 = s3 * inv;
    float v0 = fmaxf(q0 * inv - me0 * me0, 0.f);
    float v1 = fmaxf(q1 * inv - me1 * me1, 0.f);
    float v2 = fmaxf(q2 * inv - me2 * me2, 0.f);
    float v3 = fmaxf(q3 * inv - me3 * me3, 0.f);
    size_t o = (size_t)n * 512 + c;
    float4 mx = { cnt > 0 ? x0 : 0.f, cnt > 0 ? x1 : 0.f, cnt > 0 ? x2 : 0.f, cnt > 0 ? x3 : 0.f };
    float4 st = { sqrtf(v0 + 1e-5f), sqrtf(v1 + 1e-5f), sqrtf(v2 + 1e-5f), sqrtf(v3 + 1e-5f) };
    float4 me = { me0, me1, me2, me3 };
    *(float4*)(aggX + o) = mx;
    *(float4*)(aggS + o) = st;
    *(float4*)(aggM + o) = me;
}

// --------------------------- GRU elementwise --------------------------------
__global__ void k_gru(const float* __restrict__ gi, const float* __restrict__ gh,
                      float* __restrict__ hst, bf16* __restrict__ ob)
{
    int i = blockIdx.x * 256 + threadIdx.x;
    int k = i & 127;
    size_t b = (size_t)(i >> 7) * 384;
    float ir = gi[b + k],       hr = gh[b + k];
    float iz = gi[b + 128 + k], hz = gh[b + 128 + k];
    float ic = gi[b + 256 + k], hc = gh[b + 256 + k];
    float r = 1.f / (1.f + __expf(-(ir + hr)));
    float z = 1.f / (1.f + __expf(-(iz + hz)));
    float c = tanhf(ic + r * hc);
    float h = hst[i];
    float hn = (1.f - z) * c + z * h;
    hst[i] = hn;
    ob[i] = (bf16)hn;
}

__global__ void k_writeout(const float* __restrict__ of, const float* __restrict__ ea,
                           float* __restrict__ o)
{
    size_t i = (size_t)blockIdx.x * 256 + threadIdx.x;
    if (i < 524288)            o[i] = of[i];
    else if (i < 4718592)      o[i] = ea[i - 524288];
    else                       o[i] = of[i - 4718592];
}

__global__ void k_sentinel(float* __restrict__ o, float v)
{
    int i = blockIdx.x * 256 + threadIdx.x;
    o[i] = v;
}

// ===========================================================================
extern "C" void kernel_launch(void* const* d_in, const int* in_sizes, int n_in,
                              void* d_out, int out_size, void* d_ws, size_t ws_size,
                              hipStream_t stream)
{
    static const int exp_sizes[23] = {
        524288, 4194304, 131072, 24576, 384, 589824, 1536, 196608, 384,
        49152, 384, 49152, 49152, 384, 384, 65536, 256, 32768, 128,
        24576, 128, 8192, 64 };
    if (n_in != 23) { k_sentinel<<<2048, 256, 0, stream>>>((float*)d_out, 200.f); return; }
    for (int i = 0; i < 23; i++)
        if (in_sizes[i] != exp_sizes[i]) {
            k_sentinel<<<2048, 256, 0, stream>>>((float*)d_out, 60.f + 4.f * i);
            return;
        }
    if (out_size != 5242880) { k_sentinel<<<2048, 256, 0, stream>>>((float*)d_out, 52.f); return; }

    const int* eidx = (const int*)d_in[2];

    char* w = (char*)d_ws;
    size_t off = 0;
    auto alloc = [&](size_t bytes) -> char* {
        char* p = w + off;
        off = (off + bytes + 255) & ~(size_t)255;
        return p;
    };
    int*   dflag   = (int*)  alloc(256);
    int*   iflag   = (int*)  alloc(256);
    int*   srcW    = (int*)  alloc((size_t)EE * 4);
    int*   dstW    = (int*)  alloc((size_t)EE * 4);
    int*   pos     = (int*)  alloc((size_t)EE * 4);
    int*   srcord  = (int*)  alloc((size_t)EE * 4);
    float* out_f32 = (float*)alloc((size_t)NN * HH * 4);
    bf16*  out_bf  = (bf16*) alloc((size_t)NN * HH * 2);
    bf16*  m_bf    = (bf16*) alloc((size_t)NN * HH * 2);
    bf16*  ybf     = (bf16*) alloc((size_t)NN * HH * 2);
    float* ea_f32  = (float*)alloc((size_t)EE * EDD * 4);
    bf16*  eaord   = (bf16*) alloc((size_t)EE * EDD * 2);
    bf16*  wcombBf = (bf16*) alloc((size_t)THD * EDD * 2);
    float* bcombx  = (float*)alloc((size_t)1024 * 4);
    int*   counts  = (int*)  alloc((size_t)NN * 4);
    int*   offs    = (int*)  alloc((size_t)(NN + 1) * 4);
    int*   cursor  = (int*)  alloc((size_t)NN * 4);
    float* PdPs    = (float*)alloc((size_t)NN * 1024 * 4);
    float* aggX    = (float*)alloc((size_t)NN * THD * 4);
    float* aggS    = (float*)alloc((size_t)NN * THD * 4);
    float* aggM    = (float*)alloc((size_t)NN * THD * 4);
    float* encWc  = (float*)alloc((size_t)24576 * 4);
    float* encbc  = (float*)alloc((size_t)384 * 4);
    float* preWc  = (float*)alloc((size_t)589824 * 4);
    float* prebc  = (float*)alloc((size_t)1536 * 4);
    float* postbc = (float*)alloc((size_t)384 * 4);
    float* linbc  = (float*)alloc((size_t)384 * 4);
    float* bihc   = (float*)alloc((size_t)384 * 4);
    float* bhhc   = (float*)alloc((size_t)384 * 4);
    float* em1bc  = (float*)alloc((size_t)256 * 4);
    float* em1ext = (float*)alloc((size_t)512 * 4);
    float* em2bc  = (float*)alloc((size_t)128 * 4);
    float* eu1bc  = (float*)alloc((size_t)128 * 4);
    float* eu2bc  = (float*)alloc((size_t)64 * 4);
    bf16* preWbf = (bf16*)alloc((size_t)589824 * 2);
    bf16* WnodeBf= (bf16*)alloc((size_t)3 * 131072 * 2);
    bf16* postWbf= (bf16*)alloc((size_t)196608 * 2);
    bf16* linWbf = (bf16*)alloc((size_t)49152 * 2);
    bf16* WihBf  = (bf16*)alloc((size_t)49152 * 2);
    bf16* WhhBf  = (bf16*)alloc((size_t)49152 * 2);
    bf16* em1Wbf = (bf16*)alloc((size_t)65536 * 2);
    bf16* Wem1Bf = (bf16*)alloc((size_t)65536 * 2);
    bf16* em2Wbf = (bf16*)alloc((size_t)32768 * 2);
    bf16* eu1Wbf = (bf16*)alloc((size_t)24576 * 2);
    bf16* eu2Wbf = (bf16*)alloc((size_t)8192 * 2);
    // phase-shared region: Q_ord (PNA) / gi,gh (GRU) / SAB (edge)
    char* region = alloc((size_t)EE * 512 * 2);     // 67.1 MB
    bf16*  Qord = (bf16*) (region);
    float* gi   = (float*)(region);
    float* gh   = (float*)(region + 6291456);
    float* SAB  = (float*)(region);                 // [N,512] f32

    if (ws_size < off) { k_sentinel<<<2048, 256, 0, stream>>>((float*)d_out, 44.f); return; }

    // ---- index canonicalize + CSR ----
    k_detidx<<<1, 64, 0, stream>>>(eidx, iflag);
    k_extidx<<<EE / 256, 256, 0, stream>>>(eidx, srcW, dstW, iflag);
    hipMemsetAsync(counts, 0, NN * 4, stream);
    k_count<<<EE / 256, 256, 0, stream>>>(dstW, counts);
    k_scan<<<1, 1024, 0, stream>>>(counts, offs, cursor);
    k_fill<<<EE / 256, 256, 0, stream>>>(dstW, srcW, cursor, pos, srcord);

    // ---- float canonicalize ----
    k_detect<<<1, 64, 0, stream>>>(d_in[1], dflag);
    auto CF = [&](int idx, float* dst, int n) {
        k_canon_f<<<(n + 255) / 256, 256, 0, stream>>>(d_in[idx], dst, n, dflag);
    };
    auto CB = [&](int idx, bf16* dst, int n) {
        k_canon_b<<<(n + 255) / 256, 256, 0, stream>>>(d_in[idx], dst, n, dflag);
    };
    k_canon_fb<<<(NN * HH + 255) / 256, 256, 0, stream>>>(d_in[0], out_f32, out_bf, NN * HH, dflag);
    k_canon_ea<<<(EE * EDD + 255) / 256, 256, 0, stream>>>(d_in[1], ea_f32, eaord, pos, dflag);
    k_canon_fb<<<(589824 + 255) / 256, 256, 0, stream>>>(d_in[5], preWc, preWbf, 589824, dflag);
    CF(3, encWc, 24576);   CF(4, encbc, 384);   CF(6, prebc, 1536);
    CF(8, postbc, 384);    CF(10, linbc, 384);  CF(13, bihc, 384);  CF(14, bhhc, 384);
    CF(16, em1bc, 256);    CF(18, em2bc, 128);  CF(20, eu1bc, 128); CF(22, eu2bc, 64);
    CB(7, postWbf, 196608); CB(9, linWbf, 49152);
    CB(11, WihBf, 49152);   CB(12, WhhBf, 49152);
    CB(15, em1Wbf, 65536);  CB(17, em2Wbf, 32768);
    CB(19, eu1Wbf, 24576);  CB(21, eu2Wbf, 8192);
    // repacks
    k_rep_node<<<(3 * 131072) / 256, 256, 0, stream>>>(preWbf, WnodeBf);
    k_rep_em1<<<65536 / 256, 256, 0, stream>>>(em1Wbf, Wem1Bf);
    k_ext_em1b<<<2, 256, 0, stream>>>(em1bc, em1ext);

    auto GEMM = [&](const bf16* A, int lda, const bf16* Wm, int ldw, const float* bias,
                    void* C, int ldc, int M, int Nout, int K, bool relu, int om) {
        dim3 grid(M / 64, Nout / 64);
        if (relu) {
            if (om) k_mgemm<true, 1><<<grid, 256, 0, stream>>>(A, lda, Wm, ldw, bias, C, ldc, K);
            else    k_mgemm<true, 0><<<grid, 256, 0, stream>>>(A, lda, Wm, ldw, bias, C, ldc, K);
        } else {
            if (om) k_mgemm<false, 1><<<grid, 256, 0, stream>>>(A, lda, Wm, ldw, bias, C, ldc, K);
            else    k_mgemm<false, 0><<<grid, 256, 0, stream>>>(A, lda, Wm, ldw, bias, C, ldc, K);
        }
    };

    for (int l = 0; l < 3; l++) {
        const float* preW_l  = preWc  + (size_t)l * 196608;
        const float* encW_l  = encWc  + (size_t)l * 8192;
        const float* encb_l  = encbc  + (size_t)l * 128;
        const float* preb_l  = prebc  + (size_t)l * 512;
        const bf16*  Wnode_l = WnodeBf + (size_t)l * 131072;
        const bf16*  postW_l = postWbf + (size_t)l * 65536;
        const float* postb_l = postbc + (size_t)l * 128;
        const bf16*  linW_l  = linWbf + (size_t)l * 16384;
        const float* linb_l  = linbc  + (size_t)l * 128;

        // ---- PNA ----
        k_wcomb<<<THD, 64, 0, stream>>>(preW_l, encW_l, encb_l, preb_l, wcombBf, bcombx);
        GEMM(out_bf, HH, Wnode_l, 128, bcombx, PdPs, 1024, NN, 1024, HH, false, 0);
        k_qgemm<<<dim3(EE / 64, 2), 256, 0, stream>>>(eaord, wcombBf, Qord);
        k_agg<<<NN, 128, 0, stream>>>(PdPs, Qord, srcord, offs, aggX, aggS, aggM);
        k_postg<<<dim3(NN / 64, 4), 256, 0, stream>>>(out_f32, aggX, aggS, aggM,
                                                      postW_l, postb_l, ybf);
        GEMM(ybf, HH, linW_l, HH, linb_l, m_bf, HH, NN, HH, HH, true, 1);
        // ---- GRU ----
        GEMM(m_bf,   HH, WihBf, HH, bihc, gi, 384, NN, 384, HH, false, 0);
        GEMM(out_bf, HH, WhhBf, HH, bhhc, gh, 384, NN, 384, HH, false, 0);
        k_gru<<<NN * HH / 256, 256, 0, stream>>>(gi, gh, out_f32, out_bf);
        // ---- edge update (merged SAB + fused chain) ----
        GEMM(out_bf, HH, Wem1Bf, 128, em1ext, SAB, 512, NN, 512, HH, false, 0);
        k_edge<<<EE / 64, 256, 0, stream>>>(SAB, em2Wbf, em2bc, eu1Wbf, eu1bc,
                                            eu2Wbf, eu2bc, srcW, dstW, pos,
                                            eaord, ea_f32);
    }

    k_writeout<<<(2 * NN * HH + EE * EDD) / 256, 256, 0, stream>>>(out_f32, ea_f32, (float*)d_out);
}